// Round 20
// baseline (923.192 us; speedup 1.0000x reference)
//
#include <hip/hip_runtime.h>
#include <hip/hip_bf16.h>
#include <math.h>

// Problem constants
#define LAYERS 4
#define NHEAD  12
#define DMODEL 768
#define HEADD  64
#define NCTX   2048
#define NVOCAB 50257
#define NVPAD  50432            // 788*64 = 197*256
#define D3     (3*DMODEL)
#define D4     (4*DMODEL)

typedef short short8 __attribute__((ext_vector_type(8)));
typedef float f32x4  __attribute__((ext_vector_type(4)));
typedef float f32x4u __attribute__((ext_vector_type(4), aligned(4)));
typedef ushort ushx4 __attribute__((ext_vector_type(4)));

__device__ __forceinline__ float bf2f(ushort u) {
    union { uint i; float f; } c; c.i = ((uint)u) << 16; return c.f;
}
__device__ __forceinline__ ushort f2bf(float f) {
    union { float f; uint i; } c; c.f = f;
    uint i = c.i;
    uint r = (i + 0x7FFFu + ((i >> 16) & 1u)) >> 16;   // round-nearest-even
    return (ushort)r;
}

#define GLD16(gp, lp) __builtin_amdgcn_global_load_lds( \
    (__attribute__((address_space(1))) void*)(gp),      \
    (__attribute__((address_space(3))) void*)(lp), 16, 0, 0)

// vmcnt-only wait + raw barrier (no lgkmcnt drain)
#define BARS() do { asm volatile("s_waitcnt vmcnt(0)" ::: "memory"); \
                    __builtin_amdgcn_s_barrier(); } while (0)

// ---------------------------------------------------------------------------
// Embedding
// ---------------------------------------------------------------------------
__global__ void embed_k(const int* __restrict__ tok,
                        const float* __restrict__ ve,
                        const float* __restrict__ pe,
                        float* __restrict__ x) {
    int c = blockIdx.x;
    int t = tok[c];
    for (int d = threadIdx.x; d < DMODEL; d += blockDim.x)
        x[(size_t)c * DMODEL + d] = ve[(size_t)t * DMODEL + d] + pe[(size_t)c * DMODEL + d];
}

// ---------------------------------------------------------------------------
// LayerNorm: one wave per row, single pass, shuffle-only.
// ---------------------------------------------------------------------------
__global__ __launch_bounds__(256) void ln_v2(const float* __restrict__ x,
                                             const float* __restrict__ g,
                                             const float* __restrict__ b,
                                             float* __restrict__ yf,
                                             ushort* __restrict__ ybf) {
    const int w = threadIdx.x >> 6, l = threadIdx.x & 63;
    const int row = blockIdx.x * 4 + w;
    const float* xr = x + (size_t)row * DMODEL;

    f32x4 v[3];
    float s = 0.f, ss = 0.f;
    #pragma unroll
    for (int i = 0; i < 3; i++) {
        v[i] = *(const f32x4*)(xr + (l + 64 * i) * 4);
        #pragma unroll
        for (int k = 0; k < 4; k++) { s += v[i][k]; ss += v[i][k] * v[i][k]; }
    }
    #pragma unroll
    for (int off = 32; off > 0; off >>= 1) {
        s  += __shfl_xor(s, off);
        ss += __shfl_xor(ss, off);
    }
    const float mu = s * (1.f / DMODEL);
    const float var = ss * (1.f / DMODEL) - mu * mu;
    const float rstd = rsqrtf(var + 1e-5f);

    #pragma unroll
    for (int i = 0; i < 3; i++) {
        const int idx = l + 64 * i;
        f32x4 g4 = *(const f32x4*)(g + idx * 4);
        f32x4 b4 = *(const f32x4*)(b + idx * 4);
        f32x4 r;
        #pragma unroll
        for (int k = 0; k < 4; k++) r[k] = (v[i][k] - mu) * rstd * g4[k] + b4[k];
        if (yf) *(f32x4*)(yf + (size_t)row * DMODEL + idx * 4) = r;
        if (ybf) {
            ushx4 u;
            #pragma unroll
            for (int k = 0; k < 4; k++) u[k] = f2bf(r[k]);
            *(ushx4*)(ybf + (size_t)row * DMODEL + idx * 4) = u;
        }
    }
}

// ---------------------------------------------------------------------------
// Transpose + f32->bf16, 64x64 tiles, coalesced lane mapping.
// ---------------------------------------------------------------------------
__device__ __forceinline__ void transp64_body(const float* __restrict__ src,
                                              ushort* __restrict__ dst,
                                              int K, int N, int nt, int kt) {
    __shared__ float tile[64][65];
    const int t = threadIdx.x;

    {
        const int r0 = t >> 4;          // 0..15
        const int c  = (t & 15) * 4;    // 0..60
        #pragma unroll
        for (int i = 0; i < 4; i++) {
            const int r = r0 + i * 16;
            const int n = nt + c;
            const float* srow = src + (size_t)(kt + r) * N;
            f32x4 v;
            if (n + 3 < N) {
                v = *(const f32x4u*)(srow + n);
            } else {
                #pragma unroll
                for (int e = 0; e < 4; e++)
                    v[e] = (n + e < N) ? srow[n + e] : 0.f;
            }
            #pragma unroll
            for (int e = 0; e < 4; e++) tile[r][c + e] = v[e];
        }
    }
    __syncthreads();
    {
        const int nl0 = t >> 3;         // 0..31
        const int kb  = (t & 7) * 8;    // 0..56
        #pragma unroll
        for (int h = 0; h < 2; h++) {
            const int nl = nl0 + h * 32;
            short8 o;
            #pragma unroll
            for (int j = 0; j < 8; j++)
                o[j] = (short)f2bf(tile[kb + j][nl]);
            *(short8*)(dst + (size_t)(nt + nl) * K + kt + kb) = o;
        }
    }
}

__global__ __launch_bounds__(256) void transp64(const float* __restrict__ src,
                                                ushort* __restrict__ dst,
                                                int K, int N) {
    transp64_body(src, dst, K, N, blockIdx.x * 64, blockIdx.y * 64);
}

// ---------------------------------------------------------------------------
// Fused per-layer weight transposes. Grid 1728 = 432 + 144 + 576 + 576.
// ---------------------------------------------------------------------------
__global__ __launch_bounds__(256) void transp4(
    const float* __restrict__ s0, const float* __restrict__ s1,
    const float* __restrict__ s2, const float* __restrict__ s3,
    ushort* __restrict__ d0, ushort* __restrict__ d1,
    ushort* __restrict__ d2, ushort* __restrict__ d3)
{
    const int bid = blockIdx.x;
    const float* src; ushort* dst; int K, N, nx, tb;
    if (bid < 432)       { src = s0; dst = d0; K = 768;  N = 2304; nx = 36; tb = bid; }
    else if (bid < 576)  { src = s1; dst = d1; K = 768;  N = 768;  nx = 12; tb = bid - 432; }
    else if (bid < 1152) { src = s2; dst = d2; K = 768;  N = 3072; nx = 48; tb = bid - 576; }
    else                 { src = s3; dst = d3; K = 3072; N = 768;  nx = 12; tb = bid - 1152; }
    transp64_body(src, dst, K, N, (tb % nx) * 64, (tb / nx) * 64);
}

// ===========================================================================
// Layer GEMM v3: counted-vmcnt 3-buffer pipeline. 256 thr, MTx128, BK=32.
// HASADD residual source is bf16.
// ===========================================================================
template<int MT, int ACT, bool HASADD, bool OUTBF>
__global__ __launch_bounds__(256) void gemm3(
    const ushort* __restrict__ A, const ushort* __restrict__ Bt,
    const float* __restrict__ bias, const ushort* __restrict__ addsrc,
    void* __restrict__ Cout, int N, int K)
{
    constexpr int AFR  = MT / 32;
    constexpr int ABYT = MT * 64;
    constexpr int BUF  = ABYT + 8192;
    constexpr int LPS  = MT / 64 + 2;
    __shared__ __align__(16) char smem[3 * BUF];
    const int bm = blockIdx.y * MT, bn = blockIdx.x * 128;
    const int t = threadIdx.x, l = t & 63, w = t >> 6;
    const int wrb = (w >> 1) * (MT / 2), wcb = (w & 1) * 64;
    const int l15 = l & 15, lg = l >> 4;
    const int swr = ((l15 >> 1) & 3) << 4;

    const int srow = t >> 2;
    const int ssc  = ((t & 3) ^ ((srow >> 1) & 3)) * 8;
    const ushort* Abase = A  + (size_t)(bm + srow) * K + ssc;
    const ushort* Bbase = Bt + (size_t)(bn + srow) * K + ssc;

    f32x4 acc[AFR][4];
    #pragma unroll
    for (int i = 0; i < AFR; i++)
        #pragma unroll
        for (int j = 0; j < 4; j++) acc[i][j] = (f32x4)0.f;

    auto STAGE = [&](int buf, int ke) {
        ushort* as = (ushort*)(smem + buf * BUF);
        ushort* bs = (ushort*)(smem + buf * BUF + ABYT);
        #pragma unroll
        for (int i = 0; i < MT / 64; i++)
            GLD16(Abase + (size_t)i * 64 * K + ke, as + (t + i * 256) * 8);
        #pragma unroll
        for (int i = 0; i < 2; i++)
            GLD16(Bbase + (size_t)i * 64 * K + ke, bs + (t + i * 256) * 8);
    };
    auto COMPUTE = [&](int buf) {
        const char* as = smem + buf * BUF;
        const char* bs = smem + buf * BUF + ABYT;
        short8 af[AFR], bfr[4];
        #pragma unroll
        for (int f = 0; f < AFR; f++)
            af[f] = *(const short8*)(as + (((wrb + f * 16 + l15) * 64 + lg * 16) ^ swr));
        #pragma unroll
        for (int f = 0; f < 4; f++)
            bfr[f] = *(const short8*)(bs + (((wcb + f * 16 + l15) * 64 + lg * 16) ^ swr));
        __builtin_amdgcn_s_setprio(1);
        #pragma unroll
        for (int fm = 0; fm < AFR; fm++)
            #pragma unroll
            for (int fn = 0; fn < 4; fn++)
                acc[fm][fn] = __builtin_amdgcn_mfma_f32_16x16x32_bf16(
                    af[fm], bfr[fn], acc[fm][fn], 0, 0, 0);
        __builtin_amdgcn_s_setprio(0);
    };

    const int nk = K >> 5;
    STAGE(0, 0);
    STAGE(1, 32);
    int bc = 0, bs2 = 2;                      // compute buf, stage buf
    for (int kt = 0; kt < nk; kt++) {
        if (kt < nk - 1)
            asm volatile("s_waitcnt vmcnt(%0)" :: "i"(LPS) : "memory");
        else
            asm volatile("s_waitcnt vmcnt(0)" ::: "memory");
        __builtin_amdgcn_s_barrier();
        asm volatile("" ::: "memory");
        if (kt + 2 < nk) STAGE(bs2, (kt + 2) << 5);
        COMPUTE(bc);
        bc  = (bc  == 2) ? 0 : bc  + 1;
        bs2 = (bs2 == 2) ? 0 : bs2 + 1;
    }

    #pragma unroll
    for (int fn = 0; fn < 4; fn++) {
        const int col = bn + wcb + fn * 16 + l15;
        const float bi = bias[col];
        #pragma unroll
        for (int fm = 0; fm < AFR; fm++) {
            #pragma unroll
            for (int j = 0; j < 4; j++) {
                const int row = bm + wrb + fm * 16 + lg * 4 + j;
                float v = acc[fm][fn][j] + bi;
                if (ACT == 1) {
                    float u = 0.7978845608028654f * (v + 0.044715f * v * v * v);
                    v = 0.5f * v * (1.f + tanhf(u));
                }
                if (HASADD) v += bf2f(addsrc[(size_t)row * N + col]);
                if (OUTBF) ((ushort*)Cout)[(size_t)row * N + col] = f2bf(v);
                else       ((float*) Cout)[(size_t)row * N + col] = v;
            }
        }
    }
}

// ---------------------------------------------------------------------------
// Logits GEMM: 256x256 tile, 1024 threads (16 waves, 4M x 4N), BK=32.
// 2-buffer / 64 KB LDS -> 2 blocks/CU (2048 thr = full CU): inter-block
// overlap absorbs the per-step stage/barrier stall (m114 mechanism).
// Round-8-proven race-free ordering per K-step:
//   BARS (vmcnt(0)+barrier: stage(kt) fully landed, all waves finished
//   COMPUTE(kt-1)) -> STAGE(kt+1) (flies under compute; safe WAR on the
//   buffer consumed at kt-1) -> COMPUTE(kt).
// XCD-chunked bijective mapping over 1576 = 8*197 blocks.
// 4-pass LDS-staged f32 epilogue (contiguous coalesced rows).
// ---------------------------------------------------------------------------
__global__ __launch_bounds__(1024) void gemm_logits(
    const ushort* __restrict__ A, const ushort* __restrict__ Bt,
    const float* __restrict__ bias, float* __restrict__ Cout)
{
    __shared__ __align__(16) char smem[65536];   // 2 x (16 KB A + 16 KB B)
    float* Cs = (float*)smem;                     // epilogue: 64 x 256 f32

    const int pid = (blockIdx.x & 7) * 197 + (blockIdx.x >> 3);
    const int np = pid >> 3, mt = pid & 7;
    const int bm = mt * 256, bn = np * 256;
    const int t = threadIdx.x, l = t & 63, w = t >> 6;   // w 0..15
    const int wm = w >> 2, wn = w & 3;          // 4 x 4 wave grid
    const int l15 = l & 15, lg = l >> 4;
    const int swr = ((l15 >> 1) & 3) << 4;

    const int sr  = t >> 2;                     // 0..255
    const int ssc = ((t & 3) ^ ((sr >> 1) & 3)) * 8;
    const ushort* Ab = A  + (size_t)(bm + sr) * DMODEL + ssc;
    const ushort* Bb = Bt + (size_t)(bn + sr) * DMODEL + ssc;

    f32x4 acc[4][4];
    #pragma unroll
    for (int i = 0; i < 4; i++)
        #pragma unroll
        for (int j = 0; j < 4; j++) acc[i][j] = (f32x4)0.f;

    auto STAGE = [&](int buf, int ke) {
        ushort* as = (ushort*)(smem + buf * 32768);
        ushort* bs = (ushort*)(smem + buf * 32768 + 16384);
        GLD16(Ab + ke, as + t * 8);
        GLD16(Bb + ke, bs + t * 8);
    };
    auto COMPUTE = [&](int buf) {
        const char* as = smem + buf * 32768;
        const char* bs = smem + buf * 32768 + 16384;
        short8 bfr[4];
        #pragma unroll
        for (int f = 0; f < 4; f++) {
            const int r = wn * 64 + f * 16 + l15;
            bfr[f] = *(const short8*)(bs + ((r * 64 + lg * 16) ^ swr));
        }
        __builtin_amdgcn_s_setprio(1);
        #pragma unroll
        for (int fm = 0; fm < 4; fm++) {
            const int r = wm * 64 + fm * 16 + l15;
            short8 af = *(const short8*)(as + ((r * 64 + lg * 16) ^ swr));
            #pragma unroll
            for (int fn = 0; fn < 4; fn++)
                acc[fm][fn] = __builtin_amdgcn_mfma_f32_16x16x32_bf16(
                    af, bfr[fn], acc[fm][fn], 0, 0, 0);
        }
        __builtin_amdgcn_s_setprio(0);
    };

    STAGE(0, 0);
    #pragma unroll
    for (int kt = 0; kt < 24; kt++) {
        BARS();                                  // stage(kt) landed; all waves
                                                 // done reading the other buf
        if (kt + 1 < 24) STAGE((kt + 1) & 1, (kt + 1) * 32);
        COMPUTE(kt & 1);                         // stage(kt+1) flies under this
    }

    // Epilogue: 4 passes of 64 rows via LDS (all 64 KB of smem).
    #pragma unroll
    for (int p = 0; p < 4; p++) {
        __syncthreads();
        if (wm == p) {
            #pragma unroll
            for (int fm = 0; fm < 4; fm++) {
                #pragma unroll
                for (int fn = 0; fn < 4; fn++) {
                    const int ccol = wn * 64 + fn * 16 + l15;
                    const int gcol = bn + ccol;
                    const float bi = (gcol < NVOCAB) ? bias[gcol] : 0.f;
                    #pragma unroll
                    for (int j = 0; j < 4; j++)
                        Cs[(fm * 16 + lg * 4 + j) * 256 + ccol] = acc[fm][fn][j] + bi;
                }
            }
        }
        __syncthreads();
        const int grow0 = bm + p * 64;
        #pragma unroll
        for (int i = 0; i < 4; i++) {
            const int idx = t + i * 1024;
            const int rr = idx >> 6, ch = idx & 63;
            f32x4 v = *(const f32x4*)(Cs + rr * 256 + ch * 4);
            float* dst = Cout + (size_t)(grow0 + rr) * NVOCAB + bn + ch * 4;
            if (bn + 256 <= NVOCAB) {
                *(f32x4u*)dst = v;
            } else {
                #pragma unroll
                for (int e = 0; e < 4; e++)
                    if (bn + ch * 4 + e < NVOCAB) dst[e] = v[e];
            }
        }
    }
}

// ---------------------------------------------------------------------------
// Build per-(head, kv-tile) swizzled K and V^T tile images (8 KB each).
// ---------------------------------------------------------------------------
#define QBLK  64
#define KVBLK 64
__global__ __launch_bounds__(256) void qkv_tiles_k(const ushort* __restrict__ qkv,
                                                   ushort* __restrict__ Kimg,
                                                   ushort* __restrict__ Vimg) {
    __shared__ __align__(16) ushort Vt_l[4096];
    const int h = blockIdx.x;
    const int kt = blockIdx.y;
    const int k0 = kt * KVBLK;
    const int t = threadIdx.x;
    ushort* kd = Kimg + ((size_t)h * (NCTX / KVBLK) + kt) * 4096;
    ushort* vd = Vimg + ((size_t)h * (NCTX / KVBLK) + kt) * 4096;

    #pragma unroll
    for (int i = 0; i < 2; i++) {
        const int c = t + i * 256;
        const int r = c >> 3, cc = c & 7;
        short8 kv8 = *(const short8*)(qkv + (size_t)(k0 + r) * D3 + DMODEL + h * HEADD + cc * 8);
        *(short8*)(kd + (((r * 8 + cc) ^ (r & 7)) * 8)) = kv8;
        short8 vv = *(const short8*)(qkv + (size_t)(k0 + r) * D3 + 2 * DMODEL + h * HEADD + cc * 8);
        #pragma unroll
        for (int j = 0; j < 8; j++) {
            const int d = cc * 8 + j;
            const int addr = (d * 128 + r * 2) ^ ((d & 7) << 4);
            *(ushort*)((char*)Vt_l + addr) = (ushort)vv[j];
        }
    }
    __syncthreads();
    #pragma unroll
    for (int i = 0; i < 2; i++) {
        const int c = t + i * 256;
        *(short8*)(vd + c * 8) = *(const short8*)(Vt_l + c * 8);
    }
}

// ---------------------------------------------------------------------------
// One attention stream step, NO-MAX softmax variant.
// ---------------------------------------------------------------------------
__device__ __forceinline__ void attn_step(
    const short8 qf[2], f32x4 Of[4], float lpart[4],
    const ushort* Kt, const ushort* Vt, char* pw,
    int k0, int q0, int maskTile, int w, int l15, int lg)
{
    const float scale = 0.125f;
    f32x4 S[4];
    __builtin_amdgcn_s_setprio(1);
    #pragma unroll
    for (int nf = 0; nf < 4; nf++) {
        f32x4 a = (f32x4)0.f;
        #pragma unroll
        for (int s = 0; s < 2; s++) {
            const int r = nf * 16 + l15;
            const int addr = (r * 128 + s * 64 + lg * 16) ^ ((r & 7) << 4);
            short8 kf = *(const short8*)((const char*)Kt + addr);
            a = __builtin_amdgcn_mfma_f32_16x16x32_bf16(qf[s], kf, a, 0, 0, 0);
        }
        S[nf] = a;
    }
    __builtin_amdgcn_s_setprio(0);

    float p[4][4];
    if (maskTile) {
        #pragma unroll
        for (int nf = 0; nf < 4; nf++) {
            const int kvg = k0 + nf * 16 + l15;
            #pragma unroll
            for (int j = 0; j < 4; j++) {
                const int qg = q0 + w * 16 + lg * 4 + j;
                p[nf][j] = (kvg <= qg) ? __expf(S[nf][j] * scale) : 0.f;
            }
        }
    } else {
        #pragma unroll
        for (int nf = 0; nf < 4; nf++)
            #pragma unroll
            for (int j = 0; j < 4; j++)
                p[nf][j] = __expf(S[nf][j] * scale);
    }

    #pragma unroll
    for (int j = 0; j < 4; j++)
        lpart[j] += (p[0][j] + p[1][j]) + (p[2][j] + p[3][j]);

    #pragma unroll
    for (int nf = 0; nf < 4; nf++)
        #pragma unroll
        for (int j = 0; j < 4; j++) {
            const int ql = lg * 4 + j;
            const int addr = (ql * 128 + (nf * 16 + l15) * 2) ^ ((ql & 7) << 4);
            *(ushort*)(pw + addr) = f2bf(p[nf][j]);
        }

    __builtin_amdgcn_s_setprio(1);
    #pragma unroll
    for (int s = 0; s < 2; s++) {
        const int paddr = (l15 * 128 + s * 64 + lg * 16) ^ ((l15 & 7) << 4);
        short8 pf = *(const short8*)(pw + paddr);
        #pragma unroll
        for (int df = 0; df < 4; df++) {
            const int r = df * 16 + l15;
            const int vaddr = (r * 128 + s * 64 + lg * 16) ^ ((r & 7) << 4);
            short8 vf = *(const short8*)((const char*)Vt + vaddr);
            Of[df] = __builtin_amdgcn_mfma_f32_16x16x32_bf16(pf, vf, Of[df], 0, 0, 0);
        }
    }
    __builtin_amdgcn_s_setprio(0);
}

// ---------------------------------------------------------------------------
// MFMA flash attention, 8 waves: waves 0-3 own stream A (q-tile p), waves
// 4-7 own stream B (q-tile 31-p). No-max softmax (deferred row-sum).
// ---------------------------------------------------------------------------
__global__ __launch_bounds__(512) void attn_mfma2(const ushort* __restrict__ qkv,
                                                  const ushort* __restrict__ Kimg,
                                                  const ushort* __restrict__ Vimg,
                                                  ushort* __restrict__ o) {
    const int h   = blockIdx.x;
    const int qaT = blockIdx.y;          // 0..15
    const int qbT = 31 - qaT;            // 16..31
    const int t = threadIdx.x;
    const int w = t >> 6;                // 0..7
    const int strm = w >> 2;             // 0 = A (short), 1 = B (long)
    const int ws = w & 3;                // row-group within stream
    const int l = t & 63;
    const int l15 = l & 15, lg = l >> 4;

    __shared__ __align__(16) ushort Ks[2][4096];
    __shared__ __align__(16) ushort Vs[2][4096];
    __shared__ __align__(16) ushort Ps[8][1024];

    const int myqT = strm ? qbT : qaT;
    const int q0 = myqT * QBLK;
    const ushort* kbase = Kimg + (size_t)h * (NCTX / KVBLK) * 4096;
    const ushort* vbase = Vimg + (size_t)h * (NCTX / KVBLK) * 4096;
    char* pw = (char*)&Ps[w][0];

    short8 qf[2];
    {
        const int qr = q0 + ws * 16 + l15;
        #pragma unroll
        for (int s = 0; s < 2; s++)
            qf[s] = *(const short8*)(qkv + (size_t)qr * D3 + h * HEADD + s * 32 + lg * 8);
    }

    f32x4 Of[4];
    float lpart[4];
    #pragma unroll
    for (int i = 0; i < 4; i++) {
        Of[i] = (f32x4)0.f;
        lpart[i] = 0.f;
    }

    const int ntiles = qbT + 1;

    GLD16(kbase + (size_t)t * 8, &Ks[0][t * 8]);
    GLD16(vbase + (size_t)t * 8, &Vs[0][t * 8]);

    for (int kt = 0; kt < ntiles; kt++) {
        const int k0 = kt * KVBLK;
        const int cur = kt & 1;
        __syncthreads();
        if (kt + 1 < ntiles) {
            const ushort* kim = kbase + (size_t)(kt + 1) * 4096;
            const ushort* vim = vbase + (size_t)(kt + 1) * 4096;
            GLD16(kim + (size_t)t * 8, &Ks[cur ^ 1][t * 8]);
            GLD16(vim + (size_t)t * 8, &Vs[cur ^ 1][t * 8]);
        }
        if (kt <= myqT)
            attn_step(qf, Of, lpart, &Ks[cur][0], &Vs[cur][0], pw,
                      k0, q0, (kt == myqT) ? 1 : 0, ws, l15, lg);
    }

    #pragma unroll
    for (int j = 0; j < 4; j++) {
        float lsum = lpart[j];
        lsum += __shfl_xor(lsum, 1);
        lsum += __shfl_xor(lsum, 2);
        lsum += __shfl_xor(lsum, 4);
        lsum += __shfl_xor(lsum, 8);
        const float inv = 1.f / lsum;
        const int qg = q0 + ws * 16 + lg * 4 + j;
        #pragma unroll
        for (int df = 0; df < 4; df++)
            o[(size_t)qg * DMODEL + h * HEADD + df * 16 + l15] = f2bf(Of[df][j] * inv);
    }
}

// ===========================================================================
// Fallback f32 path (only if ws too small)
// ===========================================================================
__global__ void layernorm_k(const float* __restrict__ x,
                            const float* __restrict__ g,
                            const float* __restrict__ b,
                            float* __restrict__ y) {
    const int row = blockIdx.x;
    const float* xr = x + (size_t)row * DMODEL;
    __shared__ float red[256];
    const int tid = threadIdx.x;
    float s = 0.f;
    for (int d = tid; d < DMODEL; d += 256) s += xr[d];
    red[tid] = s; __syncthreads();
    for (int off = 128; off > 0; off >>= 1) {
        if (tid < off) red[tid] += red[tid + off];
        __syncthreads();
    }
    const float mu = red[0] / DMODEL;
    __syncthreads();
    float v = 0.f;
    for (int d = tid; d < DMODEL; d += 256) { float tv = xr[d] - mu; v += tv * tv; }
    red[tid] = v; __syncthreads();
    for (int off = 128; off > 0; off >>= 1) {
        if (tid < off) red[tid] += red[tid + off];
        __syncthreads();
    }
    const float rstd = rsqrtf(red[0] / DMODEL + 1e-5f);
    for (int d = tid; d < DMODEL; d += 256)
        y[(size_t)row * DMODEL + d] = (xr[d] - mu) * rstd * g[d] + b[d];
}

#define BM 64
#define BN 64
#define BK 16
__global__ __launch_bounds__(256)
void gemm_f32(const float* __restrict__ A, const float* __restrict__ B,
              const float* __restrict__ bias, const float* __restrict__ addsrc,
              float* __restrict__ C, int M, int N, int K, int act) {
    __shared__ float As[BK][BM];
    __shared__ float Bs[BK][BN];
    const int bm = blockIdx.y * BM;
    const int bn = blockIdx.x * BN;
    const int tid = threadIdx.x;
    const int tr = tid >> 4;
    const int tc = tid & 15;
    float acc[4][4] = {};
    for (int k0 = 0; k0 < K; k0 += BK) {
        #pragma unroll
        for (int i = 0; i < 4; i++) {
            int idx = tid + i * 256;
            int row = idx >> 4, col = idx & 15;
            int gm = bm + row;
            float v = 0.f;
            if (gm < M) v = A[(size_t)gm * K + (k0 + col)];
            As[col][row] = v;
        }
        #pragma unroll
        for (int i = 0; i < 4; i++) {
            int idx = tid + i * 256;
            int row = idx >> 6, col = idx & 63;
            int gn = bn + col;
            float v = 0.f;
            if (gn < N) v = B[(size_t)(k0 + row) * N + gn];
            Bs[row][col] = v;
        }
        __syncthreads();
        #pragma unroll
        for (int kk = 0; kk < BK; kk++) {
            float a[4], bb[4];
            #pragma unroll
            for (int i = 0; i < 4; i++) a[i] = As[kk][tr * 4 + i];
            #pragma unroll
            for (int j = 0; j < 4; j++) bb[j] = Bs[kk][tc * 4 + j];
            #pragma unroll
            for (int i = 0; i < 4; i++)
                #pragma unroll
                for (int j = 0; j < 4; j++)
                    acc[i][j] += a[i] * bb[j];
        }
        __syncthreads();
    }
    #pragma unroll
    for (int i = 0; i < 4; i++) {
        int gm = bm + tr * 4 + i;
        if (gm >= M) continue;
        #pragma unroll
        for (int j = 0; j < 4; j++) {
            int gn = bn + tc * 4 + j;
            if (gn >= N) continue;
            float v = acc[i][j] + (bias ? bias[gn] : 0.f);
            if (act == 1) {
                const float cst = 0.7978845608028654f;
                float tt = tanhf(cst * (v + 0.044715f * v * v * v));
                v = 0.5f * v * (1.f + tt);
            }
            if (addsrc) v += addsrc[(size_t)gm * N + gn];
            C[(size_t)gm * N + gn] = v;
        }
    }
}

__global__ __launch_bounds__(256)
void attn_k(const float* __restrict__ qkv, float* __restrict__ o) {
    const int q = blockIdx.x;
    const int h = blockIdx.y;
    const int tid = threadIdx.x;
    __shared__ float qrow[HEADD];
    __shared__ float sc[NCTX];
    __shared__ float red[256];
    __shared__ float part[4][HEADD];
    if (tid < HEADD) qrow[tid] = qkv[(size_t)q * D3 + h * HEADD + tid];
    __syncthreads();
    const float scale = 0.125f;
    float lmax = -1e30f;
    for (int k = tid; k <= q; k += 256) {
        const float* kr = qkv + (size_t)k * D3 + DMODEL + h * HEADD;
        float s = 0.f;
        #pragma unroll
        for (int d = 0; d < HEADD; d++) s += qrow[d] * kr[d];
        s *= scale;
        sc[k] = s;
        lmax = fmaxf(lmax, s);
    }
    red[tid] = lmax; __syncthreads();
    for (int off = 128; off > 0; off >>= 1) {
        if (tid < off) red[tid] = fmaxf(red[tid], red[tid + off]);
        __syncthreads();
    }
    const float m = red[0];
    __syncthreads();
    float lsum = 0.f;
    for (int k = tid; k <= q; k += 256) {
        float p = expf(sc[k] - m);
        sc[k] = p;
        lsum += p;
    }
    red[tid] = lsum; __syncthreads();
    for (int off = 128; off > 0; off >>= 1) {
        if (tid < off) red[tid] += red[tid + off];
        __syncthreads();
    }
    const float inv = 1.f / red[0];
    const int grp = tid >> 6;
    const int d = tid & 63;
    float acc = 0.f;
    for (int k = grp; k <= q; k += 4)
        acc += sc[k] * qkv[(size_t)k * D3 + 2 * DMODEL + h * HEADD + d];
    part[grp][d] = acc;
    __syncthreads();
    if (tid < HEADD) {
        float v = (part[0][tid] + part[1][tid] + part[2][tid] + part[3][tid]) * inv;
        o[(size_t)q * DMODEL + h * HEADD + tid] = v;
    }
}

// ---------------------------------------------------------------------------
// Launch
// ---------------------------------------------------------------------------
extern "C" void kernel_launch(void* const* d_in, const int* in_sizes, int n_in,
                              void* d_out, int out_size, void* d_ws, size_t ws_size,
                              hipStream_t stream) {
    const int*   tokens      = (const int*)  d_in[0];
    const float* vocab_embed = (const float*)d_in[1];
    const float* pos_embed   = (const float*)d_in[2];
    const float* ln1_g       = (const float*)d_in[3];
    const float* ln1_b       = (const float*)d_in[4];
    const float* att_w       = (const float*)d_in[5];
    const float* att_b       = (const float*)d_in[6];
    const float* attn_proj_w = (const float*)d_in[7];
    const float* attn_proj_b = (const float*)d_in[8];
    const float* ln2_g       = (const float*)d_in[9];
    const float* ln2_b       = (const float*)d_in[10];
    const float* fc_w        = (const float*)d_in[11];
    const float* fc_b        = (const float*)d_in[12];
    const float* mlp_proj_w  = (const float*)d_in[13];
    const float* mlp_proj_b  = (const float*)d_in[14];
    const float* lnf_g       = (const float*)d_in[15];
    const float* lnf_b       = (const float*)d_in[16];
    const float* out_w       = (const float*)d_in[17];
    const float* out_b       = (const float*)d_in[18];
    float* out = (float*)d_out;

    const int C = NCTX;
    dim3 blk(256);

    // ---- workspace carve for bf16 path ----
    char* wp = (char*)d_ws;
    size_t used = 0;
    auto carve = [&](size_t bytes) -> void* {
        bytes = (bytes + 255) & ~(size_t)255;
        void* p = wp + used;
        used += bytes;
        return p;
    };
    float*  x_f    = (float*) carve((size_t)C * DMODEL * 4);
    ushort* h_bf   = (ushort*)carve((size_t)C * DMODEL * 2);
    ushort* qkv_bf = (ushort*)carve((size_t)C * D3 * 2);
    ushort* o_bf   = (ushort*)carve((size_t)C * DMODEL * 2);
    ushort* mid_bf = (ushort*)carve((size_t)C * D4 * 2);
    ushort* wt_a   = (ushort*)carve((size_t)D3 * DMODEL * 2);
    ushort* wt_p   = (ushort*)carve((size_t)DMODEL * DMODEL * 2);
    ushort* wt_f   = (ushort*)carve((size_t)D4 * DMODEL * 2);
    ushort* wt_m   = (ushort*)carve((size_t)DMODEL * D4 * 2);
    ushort* wt_out = (ushort*)carve((size_t)NVPAD * DMODEL * 2);
    ushort* Kimg   = (ushort*)carve((size_t)NHEAD * (C / KVBLK) * 4096 * 2);
    ushort* Vimg   = (ushort*)carve((size_t)NHEAD * (C / KVBLK) * 4096 * 2);

    if (ws_size >= used) {
        // ================= bf16 MFMA path =================
        transp64<<<dim3(NVPAD / 64, DMODEL / 64), blk, 0, stream>>>(
            out_w, wt_out, DMODEL, NVOCAB);

        embed_k<<<dim3(C), blk, 0, stream>>>(tokens, vocab_embed, pos_embed, x_f);

        for (int l = 0; l < LAYERS; l++) {
            transp4<<<dim3(1728), blk, 0, stream>>>(
                att_w + (size_t)l * DMODEL * D3,
                attn_proj_w + (size_t)l * DMODEL * DMODEL,
                fc_w + (size_t)l * DMODEL * D4,
                mlp_proj_w + (size_t)l * D4 * DMODEL,
                wt_a, wt_p, wt_f, wt_m);

            ln_v2<<<dim3(C / 4), blk, 0, stream>>>(
                x_f, ln1_g + l * DMODEL, ln1_b + l * DMODEL, nullptr, h_bf);

            gemm3<128, 0, false, true><<<dim3(D3 / 128, C / 128), blk, 0, stream>>>(
                h_bf, wt_a, att_b + l * D3, nullptr, qkv_bf, D3, DMODEL);

            qkv_tiles_k<<<dim3(NHEAD, C / KVBLK), blk, 0, stream>>>(qkv_bf, Kimg, Vimg);

            attn_mfma2<<<dim3(NHEAD, 16), dim3(512), 0, stream>>>(qkv_bf, Kimg, Vimg, o_bf);

            gemm3<64, 0, true, false><<<dim3(DMODEL / 128, C / 64), blk, 0, stream>>>(
                o_bf, wt_p, attn_proj_b + l * DMODEL, h_bf, x_f, DMODEL, DMODEL);

            ln_v2<<<dim3(C / 4), blk, 0, stream>>>(
                x_f, ln2_g + l * DMODEL, ln2_b + l * DMODEL, nullptr, h_bf);

            gemm3<128, 1, false, true><<<dim3(D4 / 128, C / 128), blk, 0, stream>>>(
                h_bf, wt_f, fc_b + l * D4, nullptr, mid_bf, D4, DMODEL);

            gemm3<64, 0, true, false><<<dim3(DMODEL / 128, C / 64), blk, 0, stream>>>(
                mid_bf, wt_m, mlp_proj_b + l * DMODEL, h_bf, x_f, DMODEL, D4);
        }

        ln_v2<<<dim3(C / 4), blk, 0, stream>>>(x_f, lnf_g, lnf_b, nullptr, h_bf);

        gemm_logits<<<dim3(1576), dim3(1024), 0, stream>>>(h_bf, wt_out, out_b, out);
        return;
    }

    // ================= fallback f32 path =================
    const size_t n_x   = (size_t)C * DMODEL;
    const size_t n_qkv = (size_t)C * D3;
    const size_t need_bytes = (3 * n_x + n_qkv + (size_t)C * D4) * sizeof(float);

    float *x, *h, *o, *qkv, *mid;
    float* ws = (float*)d_ws;
    if (ws_size >= need_bytes) {
        x = ws; h = x + n_x; o = h + n_x; qkv = o + n_x; mid = qkv + n_qkv;
    } else {
        x = ws; h = x + n_x; o = h + n_x;
        qkv = (float*)d_out; mid = qkv + n_qkv;
    }

    embed_k<<<dim3(C), blk, 0, stream>>>(tokens, vocab_embed, pos_embed, x);
    for (int l = 0; l < LAYERS; l++) {
        const float* lw;
        layernorm_k<<<dim3(C), blk, 0, stream>>>(x, ln1_g + l * DMODEL, ln1_b + l * DMODEL, h);
        lw = att_w + (size_t)l * DMODEL * D3;
        gemm_f32<<<dim3(D3 / BN, C / BM), blk, 0, stream>>>(
            h, lw, att_b + l * D3, nullptr, qkv, C, D3, DMODEL, 0);
        attn_k<<<dim3(C, NHEAD), blk, 0, stream>>>(qkv, o);
        lw = attn_proj_w + (size_t)l * DMODEL * DMODEL;
        gemm_f32<<<dim3(DMODEL / BN, C / BM), blk, 0, stream>>>(
            o, lw, attn_proj_b + l * DMODEL, h, x, C, DMODEL, DMODEL, 0);
        layernorm_k<<<dim3(C), blk, 0, stream>>>(x, ln2_g + l * DMODEL, ln2_b + l * DMODEL, h);
        lw = fc_w + (size_t)l * DMODEL * D4;
        gemm_f32<<<dim3(D4 / BN, C / BM), blk, 0, stream>>>(
            h, lw, fc_b + l * D4, nullptr, mid, C, D4, DMODEL, 1);
        lw = mlp_proj_w + (size_t)l * D4 * DMODEL;
        gemm_f32<<<dim3(DMODEL / BN, C / BM), blk, 0, stream>>>(
            mid, lw, mlp_proj_b + l * DMODEL, h, x, C, DMODEL, D4, 0);
    }
    layernorm_k<<<dim3(C), blk, 0, stream>>>(x, lnf_g, lnf_b, h);
    gemm_f32<<<dim3((NVOCAB + BN - 1) / BN, C / BM), blk, 0, stream>>>(
        h, out_w, out_b, nullptr, out, C, NVOCAB, DMODEL, 0);
}

// Round 21
// 901.280 us; speedup vs baseline: 1.0243x; 1.0243x over previous
//
#include <hip/hip_runtime.h>
#include <hip/hip_bf16.h>
#include <math.h>

// Problem constants
#define LAYERS 4
#define NHEAD  12
#define DMODEL 768
#define HEADD  64
#define NCTX   2048
#define NVOCAB 50257
#define NVPAD  50432            // 788*64 = 197*256
#define D3     (3*DMODEL)
#define D4     (4*DMODEL)

typedef short short8 __attribute__((ext_vector_type(8)));
typedef float f32x4  __attribute__((ext_vector_type(4)));
typedef float f32x4u __attribute__((ext_vector_type(4), aligned(4)));
typedef ushort ushx4 __attribute__((ext_vector_type(4)));

__device__ __forceinline__ float bf2f(ushort u) {
    union { uint i; float f; } c; c.i = ((uint)u) << 16; return c.f;
}
__device__ __forceinline__ ushort f2bf(float f) {
    union { float f; uint i; } c; c.f = f;
    uint i = c.i;
    uint r = (i + 0x7FFFu + ((i >> 16) & 1u)) >> 16;   // round-nearest-even
    return (ushort)r;
}

#define GLD16(gp, lp) __builtin_amdgcn_global_load_lds( \
    (__attribute__((address_space(1))) void*)(gp),      \
    (__attribute__((address_space(3))) void*)(lp), 16, 0, 0)

// vmcnt-only wait + raw barrier (no lgkmcnt drain)
#define BARS() do { asm volatile("s_waitcnt vmcnt(0)" ::: "memory"); \
                    __builtin_amdgcn_s_barrier(); } while (0)

// ---------------------------------------------------------------------------
// Embedding
// ---------------------------------------------------------------------------
__global__ void embed_k(const int* __restrict__ tok,
                        const float* __restrict__ ve,
                        const float* __restrict__ pe,
                        float* __restrict__ x) {
    int c = blockIdx.x;
    int t = tok[c];
    for (int d = threadIdx.x; d < DMODEL; d += blockDim.x)
        x[(size_t)c * DMODEL + d] = ve[(size_t)t * DMODEL + d] + pe[(size_t)c * DMODEL + d];
}

// ---------------------------------------------------------------------------
// LayerNorm: one wave per row, single pass, shuffle-only.
// ---------------------------------------------------------------------------
__global__ __launch_bounds__(256) void ln_v2(const float* __restrict__ x,
                                             const float* __restrict__ g,
                                             const float* __restrict__ b,
                                             float* __restrict__ yf,
                                             ushort* __restrict__ ybf) {
    const int w = threadIdx.x >> 6, l = threadIdx.x & 63;
    const int row = blockIdx.x * 4 + w;
    const float* xr = x + (size_t)row * DMODEL;

    f32x4 v[3];
    float s = 0.f, ss = 0.f;
    #pragma unroll
    for (int i = 0; i < 3; i++) {
        v[i] = *(const f32x4*)(xr + (l + 64 * i) * 4);
        #pragma unroll
        for (int k = 0; k < 4; k++) { s += v[i][k]; ss += v[i][k] * v[i][k]; }
    }
    #pragma unroll
    for (int off = 32; off > 0; off >>= 1) {
        s  += __shfl_xor(s, off);
        ss += __shfl_xor(ss, off);
    }
    const float mu = s * (1.f / DMODEL);
    const float var = ss * (1.f / DMODEL) - mu * mu;
    const float rstd = rsqrtf(var + 1e-5f);

    #pragma unroll
    for (int i = 0; i < 3; i++) {
        const int idx = l + 64 * i;
        f32x4 g4 = *(const f32x4*)(g + idx * 4);
        f32x4 b4 = *(const f32x4*)(b + idx * 4);
        f32x4 r;
        #pragma unroll
        for (int k = 0; k < 4; k++) r[k] = (v[i][k] - mu) * rstd * g4[k] + b4[k];
        if (yf) *(f32x4*)(yf + (size_t)row * DMODEL + idx * 4) = r;
        if (ybf) {
            ushx4 u;
            #pragma unroll
            for (int k = 0; k < 4; k++) u[k] = f2bf(r[k]);
            *(ushx4*)(ybf + (size_t)row * DMODEL + idx * 4) = u;
        }
    }
}

// ---------------------------------------------------------------------------
// Transpose + f32->bf16, 64x64 tiles, coalesced lane mapping.
// ---------------------------------------------------------------------------
__device__ __forceinline__ void transp64_body(const float* __restrict__ src,
                                              ushort* __restrict__ dst,
                                              int K, int N, int nt, int kt) {
    __shared__ float tile[64][65];
    const int t = threadIdx.x;

    {
        const int r0 = t >> 4;          // 0..15
        const int c  = (t & 15) * 4;    // 0..60
        #pragma unroll
        for (int i = 0; i < 4; i++) {
            const int r = r0 + i * 16;
            const int n = nt + c;
            const float* srow = src + (size_t)(kt + r) * N;
            f32x4 v;
            if (n + 3 < N) {
                v = *(const f32x4u*)(srow + n);
            } else {
                #pragma unroll
                for (int e = 0; e < 4; e++)
                    v[e] = (n + e < N) ? srow[n + e] : 0.f;
            }
            #pragma unroll
            for (int e = 0; e < 4; e++) tile[r][c + e] = v[e];
        }
    }
    __syncthreads();
    {
        const int nl0 = t >> 3;         // 0..31
        const int kb  = (t & 7) * 8;    // 0..56
        #pragma unroll
        for (int h = 0; h < 2; h++) {
            const int nl = nl0 + h * 32;
            short8 o;
            #pragma unroll
            for (int j = 0; j < 8; j++)
                o[j] = (short)f2bf(tile[kb + j][nl]);
            *(short8*)(dst + (size_t)(nt + nl) * K + kt + kb) = o;
        }
    }
}

__global__ __launch_bounds__(256) void transp64(const float* __restrict__ src,
                                                ushort* __restrict__ dst,
                                                int K, int N) {
    transp64_body(src, dst, K, N, blockIdx.x * 64, blockIdx.y * 64);
}

// ---------------------------------------------------------------------------
// Fused per-layer weight transposes. Grid 1728 = 432 + 144 + 576 + 576.
// ---------------------------------------------------------------------------
__global__ __launch_bounds__(256) void transp4(
    const float* __restrict__ s0, const float* __restrict__ s1,
    const float* __restrict__ s2, const float* __restrict__ s3,
    ushort* __restrict__ d0, ushort* __restrict__ d1,
    ushort* __restrict__ d2, ushort* __restrict__ d3)
{
    const int bid = blockIdx.x;
    const float* src; ushort* dst; int K, N, nx, tb;
    if (bid < 432)       { src = s0; dst = d0; K = 768;  N = 2304; nx = 36; tb = bid; }
    else if (bid < 576)  { src = s1; dst = d1; K = 768;  N = 768;  nx = 12; tb = bid - 432; }
    else if (bid < 1152) { src = s2; dst = d2; K = 768;  N = 3072; nx = 48; tb = bid - 576; }
    else                 { src = s3; dst = d3; K = 3072; N = 768;  nx = 12; tb = bid - 1152; }
    transp64_body(src, dst, K, N, (tb % nx) * 64, (tb / nx) * 64);
}

// ===========================================================================
// Layer GEMM v3: counted-vmcnt 3-buffer pipeline. 256 thr, MTx128, BK=32.
// HASADD residual source is bf16.
// ===========================================================================
template<int MT, int ACT, bool HASADD, bool OUTBF>
__global__ __launch_bounds__(256) void gemm3(
    const ushort* __restrict__ A, const ushort* __restrict__ Bt,
    const float* __restrict__ bias, const ushort* __restrict__ addsrc,
    void* __restrict__ Cout, int N, int K)
{
    constexpr int AFR  = MT / 32;
    constexpr int ABYT = MT * 64;
    constexpr int BUF  = ABYT + 8192;
    constexpr int LPS  = MT / 64 + 2;
    __shared__ __align__(16) char smem[3 * BUF];
    const int bm = blockIdx.y * MT, bn = blockIdx.x * 128;
    const int t = threadIdx.x, l = t & 63, w = t >> 6;
    const int wrb = (w >> 1) * (MT / 2), wcb = (w & 1) * 64;
    const int l15 = l & 15, lg = l >> 4;
    const int swr = ((l15 >> 1) & 3) << 4;

    const int srow = t >> 2;
    const int ssc  = ((t & 3) ^ ((srow >> 1) & 3)) * 8;
    const ushort* Abase = A  + (size_t)(bm + srow) * K + ssc;
    const ushort* Bbase = Bt + (size_t)(bn + srow) * K + ssc;

    f32x4 acc[AFR][4];
    #pragma unroll
    for (int i = 0; i < AFR; i++)
        #pragma unroll
        for (int j = 0; j < 4; j++) acc[i][j] = (f32x4)0.f;

    auto STAGE = [&](int buf, int ke) {
        ushort* as = (ushort*)(smem + buf * BUF);
        ushort* bs = (ushort*)(smem + buf * BUF + ABYT);
        #pragma unroll
        for (int i = 0; i < MT / 64; i++)
            GLD16(Abase + (size_t)i * 64 * K + ke, as + (t + i * 256) * 8);
        #pragma unroll
        for (int i = 0; i < 2; i++)
            GLD16(Bbase + (size_t)i * 64 * K + ke, bs + (t + i * 256) * 8);
    };
    auto COMPUTE = [&](int buf) {
        const char* as = smem + buf * BUF;
        const char* bs = smem + buf * BUF + ABYT;
        short8 af[AFR], bfr[4];
        #pragma unroll
        for (int f = 0; f < AFR; f++)
            af[f] = *(const short8*)(as + (((wrb + f * 16 + l15) * 64 + lg * 16) ^ swr));
        #pragma unroll
        for (int f = 0; f < 4; f++)
            bfr[f] = *(const short8*)(bs + (((wcb + f * 16 + l15) * 64 + lg * 16) ^ swr));
        __builtin_amdgcn_s_setprio(1);
        #pragma unroll
        for (int fm = 0; fm < AFR; fm++)
            #pragma unroll
            for (int fn = 0; fn < 4; fn++)
                acc[fm][fn] = __builtin_amdgcn_mfma_f32_16x16x32_bf16(
                    af[fm], bfr[fn], acc[fm][fn], 0, 0, 0);
        __builtin_amdgcn_s_setprio(0);
    };

    const int nk = K >> 5;
    STAGE(0, 0);
    STAGE(1, 32);
    int bc = 0, bs2 = 2;                      // compute buf, stage buf
    for (int kt = 0; kt < nk; kt++) {
        if (kt < nk - 1)
            asm volatile("s_waitcnt vmcnt(%0)" :: "i"(LPS) : "memory");
        else
            asm volatile("s_waitcnt vmcnt(0)" ::: "memory");
        __builtin_amdgcn_s_barrier();
        asm volatile("" ::: "memory");
        if (kt + 2 < nk) STAGE(bs2, (kt + 2) << 5);
        COMPUTE(bc);
        bc  = (bc  == 2) ? 0 : bc  + 1;
        bs2 = (bs2 == 2) ? 0 : bs2 + 1;
    }

    #pragma unroll
    for (int fn = 0; fn < 4; fn++) {
        const int col = bn + wcb + fn * 16 + l15;
        const float bi = bias[col];
        #pragma unroll
        for (int fm = 0; fm < AFR; fm++) {
            #pragma unroll
            for (int j = 0; j < 4; j++) {
                const int row = bm + wrb + fm * 16 + lg * 4 + j;
                float v = acc[fm][fn][j] + bi;
                if (ACT == 1) {
                    float u = 0.7978845608028654f * (v + 0.044715f * v * v * v);
                    v = 0.5f * v * (1.f + tanhf(u));
                }
                if (HASADD) v += bf2f(addsrc[(size_t)row * N + col]);
                if (OUTBF) ((ushort*)Cout)[(size_t)row * N + col] = f2bf(v);
                else       ((float*) Cout)[(size_t)row * N + col] = v;
            }
        }
    }
}

// ---------------------------------------------------------------------------
// Logits GEMM: 256x256 tile, 1024 threads (16 waves, 4M x 4N), BK=32.
// 3-buffer counted-vmcnt pipeline (96 KB LDS, 4 waves/SIMD).
// XCD-chunked bijective mapping over 1576 = 8*197 blocks.
// 4-pass LDS-staged f32 epilogue (contiguous coalesced rows).
// ---------------------------------------------------------------------------
__global__ __launch_bounds__(1024) void gemm_logits(
    const ushort* __restrict__ A, const ushort* __restrict__ Bt,
    const float* __restrict__ bias, float* __restrict__ Cout)
{
    __shared__ __align__(16) char smem[98304];   // 3 x (16 KB A + 16 KB B)
    float* Cs = (float*)smem;                     // epilogue: 64 x 256 f32

    const int pid = (blockIdx.x & 7) * 197 + (blockIdx.x >> 3);
    const int np = pid >> 3, mt = pid & 7;
    const int bm = mt * 256, bn = np * 256;
    const int t = threadIdx.x, l = t & 63, w = t >> 6;   // w 0..15
    const int wm = w >> 2, wn = w & 3;          // 4 x 4 wave grid
    const int l15 = l & 15, lg = l >> 4;
    const int swr = ((l15 >> 1) & 3) << 4;

    const int sr  = t >> 2;                     // 0..255
    const int ssc = ((t & 3) ^ ((sr >> 1) & 3)) * 8;
    const ushort* Ab = A  + (size_t)(bm + sr) * DMODEL + ssc;
    const ushort* Bb = Bt + (size_t)(bn + sr) * DMODEL + ssc;

    f32x4 acc[4][4];
    #pragma unroll
    for (int i = 0; i < 4; i++)
        #pragma unroll
        for (int j = 0; j < 4; j++) acc[i][j] = (f32x4)0.f;

    auto STAGE = [&](int buf, int ke) {
        ushort* as = (ushort*)(smem + buf * 32768);
        ushort* bs = (ushort*)(smem + buf * 32768 + 16384);
        GLD16(Ab + ke, as + t * 8);
        GLD16(Bb + ke, bs + t * 8);
    };
    auto COMPUTE = [&](int buf) {
        const char* as = smem + buf * 32768;
        const char* bs = smem + buf * 32768 + 16384;
        short8 bfr[4];
        #pragma unroll
        for (int f = 0; f < 4; f++) {
            const int r = wn * 64 + f * 16 + l15;
            bfr[f] = *(const short8*)(bs + ((r * 64 + lg * 16) ^ swr));
        }
        __builtin_amdgcn_s_setprio(1);
        #pragma unroll
        for (int fm = 0; fm < 4; fm++) {
            const int r = wm * 64 + fm * 16 + l15;
            short8 af = *(const short8*)(as + ((r * 64 + lg * 16) ^ swr));
            #pragma unroll
            for (int fn = 0; fn < 4; fn++)
                acc[fm][fn] = __builtin_amdgcn_mfma_f32_16x16x32_bf16(
                    af, bfr[fn], acc[fm][fn], 0, 0, 0);
        }
        __builtin_amdgcn_s_setprio(0);
    };

    STAGE(0, 0);
    STAGE(1, 32);
    #pragma unroll
    for (int kt = 0; kt < 24; kt++) {
        if (kt <= 22) asm volatile("s_waitcnt vmcnt(2)" ::: "memory");
        else          asm volatile("s_waitcnt vmcnt(0)" ::: "memory");
        __builtin_amdgcn_s_barrier();
        asm volatile("" ::: "memory");
        if (kt + 2 < 24) STAGE((kt + 2) % 3, (kt + 2) * 32);
        COMPUTE(kt % 3);
    }

    // Epilogue: 4 passes of 64 rows via LDS (first 64 KB of smem).
    #pragma unroll
    for (int p = 0; p < 4; p++) {
        __syncthreads();
        if (wm == p) {
            #pragma unroll
            for (int fm = 0; fm < 4; fm++) {
                #pragma unroll
                for (int fn = 0; fn < 4; fn++) {
                    const int ccol = wn * 64 + fn * 16 + l15;
                    const int gcol = bn + ccol;
                    const float bi = (gcol < NVOCAB) ? bias[gcol] : 0.f;
                    #pragma unroll
                    for (int j = 0; j < 4; j++)
                        Cs[(fm * 16 + lg * 4 + j) * 256 + ccol] = acc[fm][fn][j] + bi;
                }
            }
        }
        __syncthreads();
        const int grow0 = bm + p * 64;
        #pragma unroll
        for (int i = 0; i < 4; i++) {
            const int idx = t + i * 1024;
            const int rr = idx >> 6, ch = idx & 63;
            f32x4 v = *(const f32x4*)(Cs + rr * 256 + ch * 4);
            float* dst = Cout + (size_t)(grow0 + rr) * NVOCAB + bn + ch * 4;
            if (bn + 256 <= NVOCAB) {
                *(f32x4u*)dst = v;
            } else {
                #pragma unroll
                for (int e = 0; e < 4; e++)
                    if (bn + ch * 4 + e < NVOCAB) dst[e] = v[e];
            }
        }
    }
}

// ---------------------------------------------------------------------------
// Build per-(head, kv-tile) swizzled K and V^T tile images (8 KB each).
// ---------------------------------------------------------------------------
#define QBLK  64
#define KVBLK 64
__global__ __launch_bounds__(256) void qkv_tiles_k(const ushort* __restrict__ qkv,
                                                   ushort* __restrict__ Kimg,
                                                   ushort* __restrict__ Vimg) {
    __shared__ __align__(16) ushort Vt_l[4096];
    const int h = blockIdx.x;
    const int kt = blockIdx.y;
    const int k0 = kt * KVBLK;
    const int t = threadIdx.x;
    ushort* kd = Kimg + ((size_t)h * (NCTX / KVBLK) + kt) * 4096;
    ushort* vd = Vimg + ((size_t)h * (NCTX / KVBLK) + kt) * 4096;

    #pragma unroll
    for (int i = 0; i < 2; i++) {
        const int c = t + i * 256;
        const int r = c >> 3, cc = c & 7;
        short8 kv8 = *(const short8*)(qkv + (size_t)(k0 + r) * D3 + DMODEL + h * HEADD + cc * 8);
        *(short8*)(kd + (((r * 8 + cc) ^ (r & 7)) * 8)) = kv8;
        short8 vv = *(const short8*)(qkv + (size_t)(k0 + r) * D3 + 2 * DMODEL + h * HEADD + cc * 8);
        #pragma unroll
        for (int j = 0; j < 8; j++) {
            const int d = cc * 8 + j;
            const int addr = (d * 128 + r * 2) ^ ((d & 7) << 4);
            *(ushort*)((char*)Vt_l + addr) = (ushort)vv[j];
        }
    }
    __syncthreads();
    #pragma unroll
    for (int i = 0; i < 2; i++) {
        const int c = t + i * 256;
        *(short8*)(vd + c * 8) = *(const short8*)(Vt_l + c * 8);
    }
}

// ---------------------------------------------------------------------------
// One attention stream step, NO-MAX softmax variant.
// ---------------------------------------------------------------------------
__device__ __forceinline__ void attn_step(
    const short8 qf[2], f32x4 Of[4], float lpart[4],
    const ushort* Kt, const ushort* Vt, char* pw,
    int k0, int q0, int maskTile, int w, int l15, int lg)
{
    const float scale = 0.125f;
    f32x4 S[4];
    __builtin_amdgcn_s_setprio(1);
    #pragma unroll
    for (int nf = 0; nf < 4; nf++) {
        f32x4 a = (f32x4)0.f;
        #pragma unroll
        for (int s = 0; s < 2; s++) {
            const int r = nf * 16 + l15;
            const int addr = (r * 128 + s * 64 + lg * 16) ^ ((r & 7) << 4);
            short8 kf = *(const short8*)((const char*)Kt + addr);
            a = __builtin_amdgcn_mfma_f32_16x16x32_bf16(qf[s], kf, a, 0, 0, 0);
        }
        S[nf] = a;
    }
    __builtin_amdgcn_s_setprio(0);

    float p[4][4];
    if (maskTile) {
        #pragma unroll
        for (int nf = 0; nf < 4; nf++) {
            const int kvg = k0 + nf * 16 + l15;
            #pragma unroll
            for (int j = 0; j < 4; j++) {
                const int qg = q0 + w * 16 + lg * 4 + j;
                p[nf][j] = (kvg <= qg) ? __expf(S[nf][j] * scale) : 0.f;
            }
        }
    } else {
        #pragma unroll
        for (int nf = 0; nf < 4; nf++)
            #pragma unroll
            for (int j = 0; j < 4; j++)
                p[nf][j] = __expf(S[nf][j] * scale);
    }

    #pragma unroll
    for (int j = 0; j < 4; j++)
        lpart[j] += (p[0][j] + p[1][j]) + (p[2][j] + p[3][j]);

    #pragma unroll
    for (int nf = 0; nf < 4; nf++)
        #pragma unroll
        for (int j = 0; j < 4; j++) {
            const int ql = lg * 4 + j;
            const int addr = (ql * 128 + (nf * 16 + l15) * 2) ^ ((ql & 7) << 4);
            *(ushort*)(pw + addr) = f2bf(p[nf][j]);
        }

    __builtin_amdgcn_s_setprio(1);
    #pragma unroll
    for (int s = 0; s < 2; s++) {
        const int paddr = (l15 * 128 + s * 64 + lg * 16) ^ ((l15 & 7) << 4);
        short8 pf = *(const short8*)(pw + paddr);
        #pragma unroll
        for (int df = 0; df < 4; df++) {
            const int r = df * 16 + l15;
            const int vaddr = (r * 128 + s * 64 + lg * 16) ^ ((r & 7) << 4);
            short8 vf = *(const short8*)((const char*)Vt + vaddr);
            Of[df] = __builtin_amdgcn_mfma_f32_16x16x32_bf16(pf, vf, Of[df], 0, 0, 0);
        }
    }
    __builtin_amdgcn_s_setprio(0);
}

// ---------------------------------------------------------------------------
// MFMA flash attention, 8 waves: waves 0-3 own stream A (q-tile p), waves
// 4-7 own stream B (q-tile 31-p). No-max softmax (deferred row-sum).
// ---------------------------------------------------------------------------
__global__ __launch_bounds__(512) void attn_mfma2(const ushort* __restrict__ qkv,
                                                  const ushort* __restrict__ Kimg,
                                                  const ushort* __restrict__ Vimg,
                                                  ushort* __restrict__ o) {
    const int h   = blockIdx.x;
    const int qaT = blockIdx.y;          // 0..15
    const int qbT = 31 - qaT;            // 16..31
    const int t = threadIdx.x;
    const int w = t >> 6;                // 0..7
    const int strm = w >> 2;             // 0 = A (short), 1 = B (long)
    const int ws = w & 3;                // row-group within stream
    const int l = t & 63;
    const int l15 = l & 15, lg = l >> 4;

    __shared__ __align__(16) ushort Ks[2][4096];
    __shared__ __align__(16) ushort Vs[2][4096];
    __shared__ __align__(16) ushort Ps[8][1024];

    const int myqT = strm ? qbT : qaT;
    const int q0 = myqT * QBLK;
    const ushort* kbase = Kimg + (size_t)h * (NCTX / KVBLK) * 4096;
    const ushort* vbase = Vimg + (size_t)h * (NCTX / KVBLK) * 4096;
    char* pw = (char*)&Ps[w][0];

    short8 qf[2];
    {
        const int qr = q0 + ws * 16 + l15;
        #pragma unroll
        for (int s = 0; s < 2; s++)
            qf[s] = *(const short8*)(qkv + (size_t)qr * D3 + h * HEADD + s * 32 + lg * 8);
    }

    f32x4 Of[4];
    float lpart[4];
    #pragma unroll
    for (int i = 0; i < 4; i++) {
        Of[i] = (f32x4)0.f;
        lpart[i] = 0.f;
    }

    const int ntiles = qbT + 1;

    GLD16(kbase + (size_t)t * 8, &Ks[0][t * 8]);
    GLD16(vbase + (size_t)t * 8, &Vs[0][t * 8]);

    for (int kt = 0; kt < ntiles; kt++) {
        const int k0 = kt * KVBLK;
        const int cur = kt & 1;
        __syncthreads();
        if (kt + 1 < ntiles) {
            const ushort* kim = kbase + (size_t)(kt + 1) * 4096;
            const ushort* vim = vbase + (size_t)(kt + 1) * 4096;
            GLD16(kim + (size_t)t * 8, &Ks[cur ^ 1][t * 8]);
            GLD16(vim + (size_t)t * 8, &Vs[cur ^ 1][t * 8]);
        }
        if (kt <= myqT)
            attn_step(qf, Of, lpart, &Ks[cur][0], &Vs[cur][0], pw,
                      k0, q0, (kt == myqT) ? 1 : 0, ws, l15, lg);
    }

    #pragma unroll
    for (int j = 0; j < 4; j++) {
        float lsum = lpart[j];
        lsum += __shfl_xor(lsum, 1);
        lsum += __shfl_xor(lsum, 2);
        lsum += __shfl_xor(lsum, 4);
        lsum += __shfl_xor(lsum, 8);
        const float inv = 1.f / lsum;
        const int qg = q0 + ws * 16 + lg * 4 + j;
        #pragma unroll
        for (int df = 0; df < 4; df++)
            o[(size_t)qg * DMODEL + h * HEADD + df * 16 + l15] = f2bf(Of[df][j] * inv);
    }
}

// ===========================================================================
// Fallback f32 path (only if ws too small)
// ===========================================================================
__global__ void layernorm_k(const float* __restrict__ x,
                            const float* __restrict__ g,
                            const float* __restrict__ b,
                            float* __restrict__ y) {
    const int row = blockIdx.x;
    const float* xr = x + (size_t)row * DMODEL;
    __shared__ float red[256];
    const int tid = threadIdx.x;
    float s = 0.f;
    for (int d = tid; d < DMODEL; d += 256) s += xr[d];
    red[tid] = s; __syncthreads();
    for (int off = 128; off > 0; off >>= 1) {
        if (tid < off) red[tid] += red[tid + off];
        __syncthreads();
    }
    const float mu = red[0] / DMODEL;
    __syncthreads();
    float v = 0.f;
    for (int d = tid; d < DMODEL; d += 256) { float tv = xr[d] - mu; v += tv * tv; }
    red[tid] = v; __syncthreads();
    for (int off = 128; off > 0; off >>= 1) {
        if (tid < off) red[tid] += red[tid + off];
        __syncthreads();
    }
    const float rstd = rsqrtf(red[0] / DMODEL + 1e-5f);
    for (int d = tid; d < DMODEL; d += 256)
        y[(size_t)row * DMODEL + d] = (xr[d] - mu) * rstd * g[d] + b[d];
}

#define BM 64
#define BN 64
#define BK 16
__global__ __launch_bounds__(256)
void gemm_f32(const float* __restrict__ A, const float* __restrict__ B,
              const float* __restrict__ bias, const float* __restrict__ addsrc,
              float* __restrict__ C, int M, int N, int K, int act) {
    __shared__ float As[BK][BM];
    __shared__ float Bs[BK][BN];
    const int bm = blockIdx.y * BM;
    const int bn = blockIdx.x * BN;
    const int tid = threadIdx.x;
    const int tr = tid >> 4;
    const int tc = tid & 15;
    float acc[4][4] = {};
    for (int k0 = 0; k0 < K; k0 += BK) {
        #pragma unroll
        for (int i = 0; i < 4; i++) {
            int idx = tid + i * 256;
            int row = idx >> 4, col = idx & 15;
            int gm = bm + row;
            float v = 0.f;
            if (gm < M) v = A[(size_t)gm * K + (k0 + col)];
            As[col][row] = v;
        }
        #pragma unroll
        for (int i = 0; i < 4; i++) {
            int idx = tid + i * 256;
            int row = idx >> 6, col = idx & 63;
            int gn = bn + col;
            float v = 0.f;
            if (gn < N) v = B[(size_t)(k0 + row) * N + gn];
            Bs[row][col] = v;
        }
        __syncthreads();
        #pragma unroll
        for (int kk = 0; kk < BK; kk++) {
            float a[4], bb[4];
            #pragma unroll
            for (int i = 0; i < 4; i++) a[i] = As[kk][tr * 4 + i];
            #pragma unroll
            for (int j = 0; j < 4; j++) bb[j] = Bs[kk][tc * 4 + j];
            #pragma unroll
            for (int i = 0; i < 4; i++)
                #pragma unroll
                for (int j = 0; j < 4; j++)
                    acc[i][j] += a[i] * bb[j];
        }
        __syncthreads();
    }
    #pragma unroll
    for (int i = 0; i < 4; i++) {
        int gm = bm + tr * 4 + i;
        if (gm >= M) continue;
        #pragma unroll
        for (int j = 0; j < 4; j++) {
            int gn = bn + tc * 4 + j;
            if (gn >= N) continue;
            float v = acc[i][j] + (bias ? bias[gn] : 0.f);
            if (act == 1) {
                const float cst = 0.7978845608028654f;
                float tt = tanhf(cst * (v + 0.044715f * v * v * v));
                v = 0.5f * v * (1.f + tt);
            }
            if (addsrc) v += addsrc[(size_t)gm * N + gn];
            C[(size_t)gm * N + gn] = v;
        }
    }
}

__global__ __launch_bounds__(256)
void attn_k(const float* __restrict__ qkv, float* __restrict__ o) {
    const int q = blockIdx.x;
    const int h = blockIdx.y;
    const int tid = threadIdx.x;
    __shared__ float qrow[HEADD];
    __shared__ float sc[NCTX];
    __shared__ float red[256];
    __shared__ float part[4][HEADD];
    if (tid < HEADD) qrow[tid] = qkv[(size_t)q * D3 + h * HEADD + tid];
    __syncthreads();
    const float scale = 0.125f;
    float lmax = -1e30f;
    for (int k = tid; k <= q; k += 256) {
        const float* kr = qkv + (size_t)k * D3 + DMODEL + h * HEADD;
        float s = 0.f;
        #pragma unroll
        for (int d = 0; d < HEADD; d++) s += qrow[d] * kr[d];
        s *= scale;
        sc[k] = s;
        lmax = fmaxf(lmax, s);
    }
    red[tid] = lmax; __syncthreads();
    for (int off = 128; off > 0; off >>= 1) {
        if (tid < off) red[tid] = fmaxf(red[tid], red[tid + off]);
        __syncthreads();
    }
    const float m = red[0];
    __syncthreads();
    float lsum = 0.f;
    for (int k = tid; k <= q; k += 256) {
        float p = expf(sc[k] - m);
        sc[k] = p;
        lsum += p;
    }
    red[tid] = lsum; __syncthreads();
    for (int off = 128; off > 0; off >>= 1) {
        if (tid < off) red[tid] += red[tid + off];
        __syncthreads();
    }
    const float inv = 1.f / red[0];
    const int grp = tid >> 6;
    const int d = tid & 63;
    float acc = 0.f;
    for (int k = grp; k <= q; k += 4)
        acc += sc[k] * qkv[(size_t)k * D3 + 2 * DMODEL + h * HEADD + d];
    part[grp][d] = acc;
    __syncthreads();
    if (tid < HEADD) {
        float v = (part[0][tid] + part[1][tid] + part[2][tid] + part[3][tid]) * inv;
        o[(size_t)q * DMODEL + h * HEADD + tid] = v;
    }
}

// ---------------------------------------------------------------------------
// Launch
// ---------------------------------------------------------------------------
extern "C" void kernel_launch(void* const* d_in, const int* in_sizes, int n_in,
                              void* d_out, int out_size, void* d_ws, size_t ws_size,
                              hipStream_t stream) {
    const int*   tokens      = (const int*)  d_in[0];
    const float* vocab_embed = (const float*)d_in[1];
    const float* pos_embed   = (const float*)d_in[2];
    const float* ln1_g       = (const float*)d_in[3];
    const float* ln1_b       = (const float*)d_in[4];
    const float* att_w       = (const float*)d_in[5];
    const float* att_b       = (const float*)d_in[6];
    const float* attn_proj_w = (const float*)d_in[7];
    const float* attn_proj_b = (const float*)d_in[8];
    const float* ln2_g       = (const float*)d_in[9];
    const float* ln2_b       = (const float*)d_in[10];
    const float* fc_w        = (const float*)d_in[11];
    const float* fc_b        = (const float*)d_in[12];
    const float* mlp_proj_w  = (const float*)d_in[13];
    const float* mlp_proj_b  = (const float*)d_in[14];
    const float* lnf_g       = (const float*)d_in[15];
    const float* lnf_b       = (const float*)d_in[16];
    const float* out_w       = (const float*)d_in[17];
    const float* out_b       = (const float*)d_in[18];
    float* out = (float*)d_out;

    const int C = NCTX;
    dim3 blk(256);

    // ---- workspace carve for bf16 path ----
    char* wp = (char*)d_ws;
    size_t used = 0;
    auto carve = [&](size_t bytes) -> void* {
        bytes = (bytes + 255) & ~(size_t)255;
        void* p = wp + used;
        used += bytes;
        return p;
    };
    float*  x_f    = (float*) carve((size_t)C * DMODEL * 4);
    ushort* h_bf   = (ushort*)carve((size_t)C * DMODEL * 2);
    ushort* qkv_bf = (ushort*)carve((size_t)C * D3 * 2);
    ushort* o_bf   = (ushort*)carve((size_t)C * DMODEL * 2);
    ushort* mid_bf = (ushort*)carve((size_t)C * D4 * 2);
    ushort* wt_a   = (ushort*)carve((size_t)D3 * DMODEL * 2);
    ushort* wt_p   = (ushort*)carve((size_t)DMODEL * DMODEL * 2);
    ushort* wt_f   = (ushort*)carve((size_t)D4 * DMODEL * 2);
    ushort* wt_m   = (ushort*)carve((size_t)DMODEL * D4 * 2);
    ushort* wt_out = (ushort*)carve((size_t)NVPAD * DMODEL * 2);
    ushort* Kimg   = (ushort*)carve((size_t)NHEAD * (C / KVBLK) * 4096 * 2);
    ushort* Vimg   = (ushort*)carve((size_t)NHEAD * (C / KVBLK) * 4096 * 2);

    if (ws_size >= used) {
        // ================= bf16 MFMA path =================
        transp64<<<dim3(NVPAD / 64, DMODEL / 64), blk, 0, stream>>>(
            out_w, wt_out, DMODEL, NVOCAB);

        embed_k<<<dim3(C), blk, 0, stream>>>(tokens, vocab_embed, pos_embed, x_f);

        for (int l = 0; l < LAYERS; l++) {
            transp4<<<dim3(1728), blk, 0, stream>>>(
                att_w + (size_t)l * DMODEL * D3,
                attn_proj_w + (size_t)l * DMODEL * DMODEL,
                fc_w + (size_t)l * DMODEL * D4,
                mlp_proj_w + (size_t)l * D4 * DMODEL,
                wt_a, wt_p, wt_f, wt_m);

            ln_v2<<<dim3(C / 4), blk, 0, stream>>>(
                x_f, ln1_g + l * DMODEL, ln1_b + l * DMODEL, nullptr, h_bf);

            gemm3<128, 0, false, true><<<dim3(D3 / 128, C / 128), blk, 0, stream>>>(
                h_bf, wt_a, att_b + l * D3, nullptr, qkv_bf, D3, DMODEL);

            qkv_tiles_k<<<dim3(NHEAD, C / KVBLK), blk, 0, stream>>>(qkv_bf, Kimg, Vimg);

            attn_mfma2<<<dim3(NHEAD, 16), dim3(512), 0, stream>>>(qkv_bf, Kimg, Vimg, o_bf);

            gemm3<64, 0, true, false><<<dim3(DMODEL / 128, C / 64), blk, 0, stream>>>(
                o_bf, wt_p, attn_proj_b + l * DMODEL, h_bf, x_f, DMODEL, DMODEL);

            ln_v2<<<dim3(C / 4), blk, 0, stream>>>(
                x_f, ln2_g + l * DMODEL, ln2_b + l * DMODEL, nullptr, h_bf);

            gemm3<128, 1, false, true><<<dim3(D4 / 128, C / 128), blk, 0, stream>>>(
                h_bf, wt_f, fc_b + l * D4, nullptr, mid_bf, D4, DMODEL);

            gemm3<64, 0, true, false><<<dim3(DMODEL / 128, C / 64), blk, 0, stream>>>(
                mid_bf, wt_m, mlp_proj_b + l * DMODEL, h_bf, x_f, DMODEL, D4);
        }

        ln_v2<<<dim3(C / 4), blk, 0, stream>>>(x_f, lnf_g, lnf_b, nullptr, h_bf);

        gemm_logits<<<dim3(1576), dim3(1024), 0, stream>>>(h_bf, wt_out, out_b, out);
        return;
    }

    // ================= fallback f32 path =================
    const size_t n_x   = (size_t)C * DMODEL;
    const size_t n_qkv = (size_t)C * D3;
    const size_t need_bytes = (3 * n_x + n_qkv + (size_t)C * D4) * sizeof(float);

    float *x, *h, *o, *qkv, *mid;
    float* ws = (float*)d_ws;
    if (ws_size >= need_bytes) {
        x = ws; h = x + n_x; o = h + n_x; qkv = o + n_x; mid = qkv + n_qkv;
    } else {
        x = ws; h = x + n_x; o = h + n_x;
        qkv = (float*)d_out; mid = qkv + n_qkv;
    }

    embed_k<<<dim3(C), blk, 0, stream>>>(tokens, vocab_embed, pos_embed, x);
    for (int l = 0; l < LAYERS; l++) {
        const float* lw;
        layernorm_k<<<dim3(C), blk, 0, stream>>>(x, ln1_g + l * DMODEL, ln1_b + l * DMODEL, h);
        lw = att_w + (size_t)l * DMODEL * D3;
        gemm_f32<<<dim3(D3 / BN, C / BM), blk, 0, stream>>>(
            h, lw, att_b + l * D3, nullptr, qkv, C, D3, DMODEL, 0);
        attn_k<<<dim3(C, NHEAD), blk, 0, stream>>>(qkv, o);
        lw = attn_proj_w + (size_t)l * DMODEL * DMODEL;
        gemm_f32<<<dim3(DMODEL / BN, C / BM), blk, 0, stream>>>(
            o, lw, attn_proj_b + l * DMODEL, h, x, C, DMODEL, DMODEL, 0);
        layernorm_k<<<dim3(C), blk, 0, stream>>>(x, ln2_g + l * DMODEL, ln2_b + l * DMODEL, h);
        lw = fc_w + (size_t)l * DMODEL * D4;
        gemm_f32<<<dim3(D4 / BN, C / BM), blk, 0, stream>>>(
            h, lw, fc_b + l * D4, nullptr, mid, C, D4, DMODEL, 1);
        lw = mlp_proj_w + (size_t)l * D4 * DMODEL;
        gemm_f32<<<dim3(DMODEL / BN, C / BM), blk, 0, stream>>>(
            mid, lw, mlp_proj_b + l * DMODEL, h, x, C, DMODEL, D4, 0);
    }
    layernorm_k<<<dim3(C), blk, 0, stream>>>(x, lnf_g, lnf_b, h);
    gemm_f32<<<dim3((NVOCAB + BN - 1) / BN, C / BM), blk, 0, stream>>>(
        h, out_w, out_b, nullptr, out, C, NVOCAB, DMODEL, 0);
}

// Round 22
// 880.514 us; speedup vs baseline: 1.0485x; 1.0236x over previous
//
#include <hip/hip_runtime.h>
#include <hip/hip_bf16.h>
#include <math.h>

// Problem constants
#define LAYERS 4
#define NHEAD  12
#define DMODEL 768
#define HEADD  64
#define NCTX   2048
#define NVOCAB 50257
#define NVPAD  50432            // 788*64 = 197*256
#define D3     (3*DMODEL)
#define D4     (4*DMODEL)

typedef short short8 __attribute__((ext_vector_type(8)));
typedef float f32x4  __attribute__((ext_vector_type(4)));
typedef float f32x4u __attribute__((ext_vector_type(4), aligned(4)));
typedef ushort ushx4 __attribute__((ext_vector_type(4)));

__device__ __forceinline__ float bf2f(ushort u) {
    union { uint i; float f; } c; c.i = ((uint)u) << 16; return c.f;
}
__device__ __forceinline__ ushort f2bf(float f) {
    union { float f; uint i; } c; c.f = f;
    uint i = c.i;
    uint r = (i + 0x7FFFu + ((i >> 16) & 1u)) >> 16;   // round-nearest-even
    return (ushort)r;
}

#define GLD16(gp, lp) __builtin_amdgcn_global_load_lds( \
    (__attribute__((address_space(1))) void*)(gp),      \
    (__attribute__((address_space(3))) void*)(lp), 16, 0, 0)

// vmcnt-only wait + raw barrier (no lgkmcnt drain)
#define BARS() do { asm volatile("s_waitcnt vmcnt(0)" ::: "memory"); \
                    __builtin_amdgcn_s_barrier(); } while (0)

// ---------------------------------------------------------------------------
// Embedding
// ---------------------------------------------------------------------------
__global__ void embed_k(const int* __restrict__ tok,
                        const float* __restrict__ ve,
                        const float* __restrict__ pe,
                        float* __restrict__ x) {
    int c = blockIdx.x;
    int t = tok[c];
    for (int d = threadIdx.x; d < DMODEL; d += blockDim.x)
        x[(size_t)c * DMODEL + d] = ve[(size_t)t * DMODEL + d] + pe[(size_t)c * DMODEL + d];
}

// ---------------------------------------------------------------------------
// LayerNorm: one wave per row, single pass, shuffle-only.
// ---------------------------------------------------------------------------
__global__ __launch_bounds__(256) void ln_v2(const float* __restrict__ x,
                                             const float* __restrict__ g,
                                             const float* __restrict__ b,
                                             float* __restrict__ yf,
                                             ushort* __restrict__ ybf) {
    const int w = threadIdx.x >> 6, l = threadIdx.x & 63;
    const int row = blockIdx.x * 4 + w;
    const float* xr = x + (size_t)row * DMODEL;

    f32x4 v[3];
    float s = 0.f, ss = 0.f;
    #pragma unroll
    for (int i = 0; i < 3; i++) {
        v[i] = *(const f32x4*)(xr + (l + 64 * i) * 4);
        #pragma unroll
        for (int k = 0; k < 4; k++) { s += v[i][k]; ss += v[i][k] * v[i][k]; }
    }
    #pragma unroll
    for (int off = 32; off > 0; off >>= 1) {
        s  += __shfl_xor(s, off);
        ss += __shfl_xor(ss, off);
    }
    const float mu = s * (1.f / DMODEL);
    const float var = ss * (1.f / DMODEL) - mu * mu;
    const float rstd = rsqrtf(var + 1e-5f);

    #pragma unroll
    for (int i = 0; i < 3; i++) {
        const int idx = l + 64 * i;
        f32x4 g4 = *(const f32x4*)(g + idx * 4);
        f32x4 b4 = *(const f32x4*)(b + idx * 4);
        f32x4 r;
        #pragma unroll
        for (int k = 0; k < 4; k++) r[k] = (v[i][k] - mu) * rstd * g4[k] + b4[k];
        if (yf) *(f32x4*)(yf + (size_t)row * DMODEL + idx * 4) = r;
        if (ybf) {
            ushx4 u;
            #pragma unroll
            for (int k = 0; k < 4; k++) u[k] = f2bf(r[k]);
            *(ushx4*)(ybf + (size_t)row * DMODEL + idx * 4) = u;
        }
    }
}

// ---------------------------------------------------------------------------
// Transpose + f32->bf16, 64x64 tiles, coalesced lane mapping.
// ---------------------------------------------------------------------------
__device__ __forceinline__ void transp64_body(const float* __restrict__ src,
                                              ushort* __restrict__ dst,
                                              int K, int N, int nt, int kt) {
    __shared__ float tile[64][65];
    const int t = threadIdx.x;

    {
        const int r0 = t >> 4;          // 0..15
        const int c  = (t & 15) * 4;    // 0..60
        #pragma unroll
        for (int i = 0; i < 4; i++) {
            const int r = r0 + i * 16;
            const int n = nt + c;
            const float* srow = src + (size_t)(kt + r) * N;
            f32x4 v;
            if (n + 3 < N) {
                v = *(const f32x4u*)(srow + n);
            } else {
                #pragma unroll
                for (int e = 0; e < 4; e++)
                    v[e] = (n + e < N) ? srow[n + e] : 0.f;
            }
            #pragma unroll
            for (int e = 0; e < 4; e++) tile[r][c + e] = v[e];
        }
    }
    __syncthreads();
    {
        const int nl0 = t >> 3;         // 0..31
        const int kb  = (t & 7) * 8;    // 0..56
        #pragma unroll
        for (int h = 0; h < 2; h++) {
            const int nl = nl0 + h * 32;
            short8 o;
            #pragma unroll
            for (int j = 0; j < 8; j++)
                o[j] = (short)f2bf(tile[kb + j][nl]);
            *(short8*)(dst + (size_t)(nt + nl) * K + kt + kb) = o;
        }
    }
}

__global__ __launch_bounds__(256) void transp64(const float* __restrict__ src,
                                                ushort* __restrict__ dst,
                                                int K, int N) {
    transp64_body(src, dst, K, N, blockIdx.x * 64, blockIdx.y * 64);
}

// ---------------------------------------------------------------------------
// Fused per-layer weight transposes. Grid 1728 = 432 + 144 + 576 + 576.
// ---------------------------------------------------------------------------
__global__ __launch_bounds__(256) void transp4(
    const float* __restrict__ s0, const float* __restrict__ s1,
    const float* __restrict__ s2, const float* __restrict__ s3,
    ushort* __restrict__ d0, ushort* __restrict__ d1,
    ushort* __restrict__ d2, ushort* __restrict__ d3)
{
    const int bid = blockIdx.x;
    const float* src; ushort* dst; int K, N, nx, tb;
    if (bid < 432)       { src = s0; dst = d0; K = 768;  N = 2304; nx = 36; tb = bid; }
    else if (bid < 576)  { src = s1; dst = d1; K = 768;  N = 768;  nx = 12; tb = bid - 432; }
    else if (bid < 1152) { src = s2; dst = d2; K = 768;  N = 3072; nx = 48; tb = bid - 576; }
    else                 { src = s3; dst = d3; K = 3072; N = 768;  nx = 12; tb = bid - 1152; }
    transp64_body(src, dst, K, N, (tb % nx) * 64, (tb / nx) * 64);
}

// ===========================================================================
// Layer GEMM v3: counted-vmcnt 3-buffer pipeline. 256 thr, MTx128, BK=32.
// HASADD residual source is bf16.
// ===========================================================================
template<int MT, int ACT, bool HASADD, bool OUTBF>
__global__ __launch_bounds__(256) void gemm3(
    const ushort* __restrict__ A, const ushort* __restrict__ Bt,
    const float* __restrict__ bias, const ushort* __restrict__ addsrc,
    void* __restrict__ Cout, int N, int K)
{
    constexpr int AFR  = MT / 32;
    constexpr int ABYT = MT * 64;
    constexpr int BUF  = ABYT + 8192;
    constexpr int LPS  = MT / 64 + 2;
    __shared__ __align__(16) char smem[3 * BUF];
    const int bm = blockIdx.y * MT, bn = blockIdx.x * 128;
    const int t = threadIdx.x, l = t & 63, w = t >> 6;
    const int wrb = (w >> 1) * (MT / 2), wcb = (w & 1) * 64;
    const int l15 = l & 15, lg = l >> 4;
    const int swr = ((l15 >> 1) & 3) << 4;

    const int srow = t >> 2;
    const int ssc  = ((t & 3) ^ ((srow >> 1) & 3)) * 8;
    const ushort* Abase = A  + (size_t)(bm + srow) * K + ssc;
    const ushort* Bbase = Bt + (size_t)(bn + srow) * K + ssc;

    f32x4 acc[AFR][4];
    #pragma unroll
    for (int i = 0; i < AFR; i++)
        #pragma unroll
        for (int j = 0; j < 4; j++) acc[i][j] = (f32x4)0.f;

    auto STAGE = [&](int buf, int ke) {
        ushort* as = (ushort*)(smem + buf * BUF);
        ushort* bs = (ushort*)(smem + buf * BUF + ABYT);
        #pragma unroll
        for (int i = 0; i < MT / 64; i++)
            GLD16(Abase + (size_t)i * 64 * K + ke, as + (t + i * 256) * 8);
        #pragma unroll
        for (int i = 0; i < 2; i++)
            GLD16(Bbase + (size_t)i * 64 * K + ke, bs + (t + i * 256) * 8);
    };
    auto COMPUTE = [&](int buf) {
        const char* as = smem + buf * BUF;
        const char* bs = smem + buf * BUF + ABYT;
        short8 af[AFR], bfr[4];
        #pragma unroll
        for (int f = 0; f < AFR; f++)
            af[f] = *(const short8*)(as + (((wrb + f * 16 + l15) * 64 + lg * 16) ^ swr));
        #pragma unroll
        for (int f = 0; f < 4; f++)
            bfr[f] = *(const short8*)(bs + (((wcb + f * 16 + l15) * 64 + lg * 16) ^ swr));
        __builtin_amdgcn_s_setprio(1);
        #pragma unroll
        for (int fm = 0; fm < AFR; fm++)
            #pragma unroll
            for (int fn = 0; fn < 4; fn++)
                acc[fm][fn] = __builtin_amdgcn_mfma_f32_16x16x32_bf16(
                    af[fm], bfr[fn], acc[fm][fn], 0, 0, 0);
        __builtin_amdgcn_s_setprio(0);
    };

    const int nk = K >> 5;
    STAGE(0, 0);
    STAGE(1, 32);
    int bc = 0, bs2 = 2;                      // compute buf, stage buf
    for (int kt = 0; kt < nk; kt++) {
        if (kt < nk - 1)
            asm volatile("s_waitcnt vmcnt(%0)" :: "i"(LPS) : "memory");
        else
            asm volatile("s_waitcnt vmcnt(0)" ::: "memory");
        __builtin_amdgcn_s_barrier();
        asm volatile("" ::: "memory");
        if (kt + 2 < nk) STAGE(bs2, (kt + 2) << 5);
        COMPUTE(bc);
        bc  = (bc  == 2) ? 0 : bc  + 1;
        bs2 = (bs2 == 2) ? 0 : bs2 + 1;
    }

    #pragma unroll
    for (int fn = 0; fn < 4; fn++) {
        const int col = bn + wcb + fn * 16 + l15;
        const float bi = bias[col];
        #pragma unroll
        for (int fm = 0; fm < AFR; fm++) {
            #pragma unroll
            for (int j = 0; j < 4; j++) {
                const int row = bm + wrb + fm * 16 + lg * 4 + j;
                float v = acc[fm][fn][j] + bi;
                if (ACT == 1) {
                    float u = 0.7978845608028654f * (v + 0.044715f * v * v * v);
                    v = 0.5f * v * (1.f + tanhf(u));
                }
                if (HASADD) v += bf2f(addsrc[(size_t)row * N + col]);
                if (OUTBF) ((ushort*)Cout)[(size_t)row * N + col] = f2bf(v);
                else       ((float*) Cout)[(size_t)row * N + col] = v;
            }
        }
    }
}

// ---------------------------------------------------------------------------
// Logits GEMM: 256x256 tile, 1024 threads (16 waves, 4M x 4N), BK=32.
// 3-buffer counted-vmcnt pipeline (96 KB LDS, 4 waves/SIMD).
// XCD-chunked bijective mapping over 1576 = 8*197 blocks.
// 4-pass LDS-staged f32 epilogue (contiguous coalesced rows).
// ---------------------------------------------------------------------------
__global__ __launch_bounds__(1024) void gemm_logits(
    const ushort* __restrict__ A, const ushort* __restrict__ Bt,
    const float* __restrict__ bias, float* __restrict__ Cout)
{
    __shared__ __align__(16) char smem[98304];   // 3 x (16 KB A + 16 KB B)
    float* Cs = (float*)smem;                     // epilogue: 64 x 256 f32

    const int pid = (blockIdx.x & 7) * 197 + (blockIdx.x >> 3);
    const int np = pid >> 3, mt = pid & 7;
    const int bm = mt * 256, bn = np * 256;
    const int t = threadIdx.x, l = t & 63, w = t >> 6;   // w 0..15
    const int wm = w >> 2, wn = w & 3;          // 4 x 4 wave grid
    const int l15 = l & 15, lg = l >> 4;
    const int swr = ((l15 >> 1) & 3) << 4;

    const int sr  = t >> 2;                     // 0..255
    const int ssc = ((t & 3) ^ ((sr >> 1) & 3)) * 8;
    const ushort* Ab = A  + (size_t)(bm + sr) * DMODEL + ssc;
    const ushort* Bb = Bt + (size_t)(bn + sr) * DMODEL + ssc;

    f32x4 acc[4][4];
    #pragma unroll
    for (int i = 0; i < 4; i++)
        #pragma unroll
        for (int j = 0; j < 4; j++) acc[i][j] = (f32x4)0.f;

    auto STAGE = [&](int buf, int ke) {
        ushort* as = (ushort*)(smem + buf * 32768);
        ushort* bs = (ushort*)(smem + buf * 32768 + 16384);
        GLD16(Ab + ke, as + t * 8);
        GLD16(Bb + ke, bs + t * 8);
    };
    auto COMPUTE = [&](int buf) {
        const char* as = smem + buf * 32768;
        const char* bs = smem + buf * 32768 + 16384;
        short8 bfr[4];
        #pragma unroll
        for (int f = 0; f < 4; f++) {
            const int r = wn * 64 + f * 16 + l15;
            bfr[f] = *(const short8*)(bs + ((r * 64 + lg * 16) ^ swr));
        }
        __builtin_amdgcn_s_setprio(1);
        #pragma unroll
        for (int fm = 0; fm < 4; fm++) {
            const int r = wm * 64 + fm * 16 + l15;
            short8 af = *(const short8*)(as + ((r * 64 + lg * 16) ^ swr));
            #pragma unroll
            for (int fn = 0; fn < 4; fn++)
                acc[fm][fn] = __builtin_amdgcn_mfma_f32_16x16x32_bf16(
                    af, bfr[fn], acc[fm][fn], 0, 0, 0);
        }
        __builtin_amdgcn_s_setprio(0);
    };

    STAGE(0, 0);
    STAGE(1, 32);
    #pragma unroll
    for (int kt = 0; kt < 24; kt++) {
        if (kt <= 22) asm volatile("s_waitcnt vmcnt(2)" ::: "memory");
        else          asm volatile("s_waitcnt vmcnt(0)" ::: "memory");
        __builtin_amdgcn_s_barrier();
        asm volatile("" ::: "memory");
        if (kt + 2 < 24) STAGE((kt + 2) % 3, (kt + 2) * 32);
        COMPUTE(kt % 3);
    }

    // Epilogue: 4 passes of 64 rows via LDS (first 64 KB of smem).
    #pragma unroll
    for (int p = 0; p < 4; p++) {
        __syncthreads();
        if (wm == p) {
            #pragma unroll
            for (int fm = 0; fm < 4; fm++) {
                #pragma unroll
                for (int fn = 0; fn < 4; fn++) {
                    const int ccol = wn * 64 + fn * 16 + l15;
                    const int gcol = bn + ccol;
                    const float bi = (gcol < NVOCAB) ? bias[gcol] : 0.f;
                    #pragma unroll
                    for (int j = 0; j < 4; j++)
                        Cs[(fm * 16 + lg * 4 + j) * 256 + ccol] = acc[fm][fn][j] + bi;
                }
            }
        }
        __syncthreads();
        const int grow0 = bm + p * 64;
        #pragma unroll
        for (int i = 0; i < 4; i++) {
            const int idx = t + i * 1024;
            const int rr = idx >> 6, ch = idx & 63;
            f32x4 v = *(const f32x4*)(Cs + rr * 256 + ch * 4);
            float* dst = Cout + (size_t)(grow0 + rr) * NVOCAB + bn + ch * 4;
            if (bn + 256 <= NVOCAB) {
                *(f32x4u*)dst = v;
            } else {
                #pragma unroll
                for (int e = 0; e < 4; e++)
                    if (bn + ch * 4 + e < NVOCAB) dst[e] = v[e];
            }
        }
    }
}

// ---------------------------------------------------------------------------
// Build per-(head, kv-tile) swizzled K and V^T tile images (8 KB each).
// ---------------------------------------------------------------------------
#define QBLK  64
#define KVBLK 64
__global__ __launch_bounds__(256) void qkv_tiles_k(const ushort* __restrict__ qkv,
                                                   ushort* __restrict__ Kimg,
                                                   ushort* __restrict__ Vimg) {
    __shared__ __align__(16) ushort Vt_l[4096];
    const int h = blockIdx.x;
    const int kt = blockIdx.y;
    const int k0 = kt * KVBLK;
    const int t = threadIdx.x;
    ushort* kd = Kimg + ((size_t)h * (NCTX / KVBLK) + kt) * 4096;
    ushort* vd = Vimg + ((size_t)h * (NCTX / KVBLK) + kt) * 4096;

    #pragma unroll
    for (int i = 0; i < 2; i++) {
        const int c = t + i * 256;
        const int r = c >> 3, cc = c & 7;
        short8 kv8 = *(const short8*)(qkv + (size_t)(k0 + r) * D3 + DMODEL + h * HEADD + cc * 8);
        *(short8*)(kd + (((r * 8 + cc) ^ (r & 7)) * 8)) = kv8;
        short8 vv = *(const short8*)(qkv + (size_t)(k0 + r) * D3 + 2 * DMODEL + h * HEADD + cc * 8);
        #pragma unroll
        for (int j = 0; j < 8; j++) {
            const int d = cc * 8 + j;
            const int addr = (d * 128 + r * 2) ^ ((d & 7) << 4);
            *(ushort*)((char*)Vt_l + addr) = (ushort)vv[j];
        }
    }
    __syncthreads();
    #pragma unroll
    for (int i = 0; i < 2; i++) {
        const int c = t + i * 256;
        *(short8*)(vd + c * 8) = *(const short8*)(Vt_l + c * 8);
    }
}

// ---------------------------------------------------------------------------
// One attention stream step, NO-MAX softmax variant.
// ---------------------------------------------------------------------------
__device__ __forceinline__ void attn_step(
    const short8 qf[2], f32x4 Of[4], float lpart[4],
    const ushort* Kt, const ushort* Vt, char* pw,
    int k0, int q0, int maskTile, int w, int l15, int lg)
{
    const float scale = 0.125f;
    f32x4 S[4];
    __builtin_amdgcn_s_setprio(1);
    #pragma unroll
    for (int nf = 0; nf < 4; nf++) {
        f32x4 a = (f32x4)0.f;
        #pragma unroll
        for (int s = 0; s < 2; s++) {
            const int r = nf * 16 + l15;
            const int addr = (r * 128 + s * 64 + lg * 16) ^ ((r & 7) << 4);
            short8 kf = *(const short8*)((const char*)Kt + addr);
            a = __builtin_amdgcn_mfma_f32_16x16x32_bf16(qf[s], kf, a, 0, 0, 0);
        }
        S[nf] = a;
    }
    __builtin_amdgcn_s_setprio(0);

    float p[4][4];
    if (maskTile) {
        #pragma unroll
        for (int nf = 0; nf < 4; nf++) {
            const int kvg = k0 + nf * 16 + l15;
            #pragma unroll
            for (int j = 0; j < 4; j++) {
                const int qg = q0 + w * 16 + lg * 4 + j;
                p[nf][j] = (kvg <= qg) ? __expf(S[nf][j] * scale) : 0.f;
            }
        }
    } else {
        #pragma unroll
        for (int nf = 0; nf < 4; nf++)
            #pragma unroll
            for (int j = 0; j < 4; j++)
                p[nf][j] = __expf(S[nf][j] * scale);
    }

    #pragma unroll
    for (int j = 0; j < 4; j++)
        lpart[j] += (p[0][j] + p[1][j]) + (p[2][j] + p[3][j]);

    #pragma unroll
    for (int nf = 0; nf < 4; nf++)
        #pragma unroll
        for (int j = 0; j < 4; j++) {
            const int ql = lg * 4 + j;
            const int addr = (ql * 128 + (nf * 16 + l15) * 2) ^ ((ql & 7) << 4);
            *(ushort*)(pw + addr) = f2bf(p[nf][j]);
        }

    __builtin_amdgcn_s_setprio(1);
    #pragma unroll
    for (int s = 0; s < 2; s++) {
        const int paddr = (l15 * 128 + s * 64 + lg * 16) ^ ((l15 & 7) << 4);
        short8 pf = *(const short8*)(pw + paddr);
        #pragma unroll
        for (int df = 0; df < 4; df++) {
            const int r = df * 16 + l15;
            const int vaddr = (r * 128 + s * 64 + lg * 16) ^ ((r & 7) << 4);
            short8 vf = *(const short8*)((const char*)Vt + vaddr);
            Of[df] = __builtin_amdgcn_mfma_f32_16x16x32_bf16(pf, vf, Of[df], 0, 0, 0);
        }
    }
    __builtin_amdgcn_s_setprio(0);
}

// ---------------------------------------------------------------------------
// MFMA flash attention, 8 waves, stream-split, PAIRED KV tiles:
// two 64-col tiles staged per barrier period (16 KB contiguous in the image),
// attn_step called per sub-tile. Halves barrier count; prefetch covered by
// 2x compute. LDS 80 KB (1 block/CU; grid 192 so residency unchanged).
// ---------------------------------------------------------------------------
__global__ __launch_bounds__(512) void attn_mfma2(const ushort* __restrict__ qkv,
                                                  const ushort* __restrict__ Kimg,
                                                  const ushort* __restrict__ Vimg,
                                                  ushort* __restrict__ o) {
    const int h   = blockIdx.x;
    const int qaT = blockIdx.y;          // 0..15
    const int qbT = 31 - qaT;            // 16..31
    const int t = threadIdx.x;
    const int w = t >> 6;                // 0..7
    const int strm = w >> 2;             // 0 = A (short), 1 = B (long)
    const int ws = w & 3;                // row-group within stream
    const int l = t & 63;
    const int l15 = l & 15, lg = l >> 4;

    __shared__ __align__(16) ushort Ks[2][8192];   // 2 x pair of 64-tiles
    __shared__ __align__(16) ushort Vs[2][8192];
    __shared__ __align__(16) ushort Ps[8][1024];

    const int myqT = strm ? qbT : qaT;
    const int q0 = myqT * QBLK;
    const ushort* kbase = Kimg + (size_t)h * (NCTX / KVBLK) * 4096;
    const ushort* vbase = Vimg + (size_t)h * (NCTX / KVBLK) * 4096;
    char* pw = (char*)&Ps[w][0];

    short8 qf[2];
    {
        const int qr = q0 + ws * 16 + l15;
        #pragma unroll
        for (int s = 0; s < 2; s++)
            qf[s] = *(const short8*)(qkv + (size_t)qr * D3 + h * HEADD + s * 32 + lg * 8);
    }

    f32x4 Of[4];
    float lpart[4];
    #pragma unroll
    for (int i = 0; i < 4; i++) {
        Of[i] = (f32x4)0.f;
        lpart[i] = 0.f;
    }

    const int ntiles = qbT + 1;              // 17..32 (64-col tiles)
    const int nsteps = (ntiles + 1) >> 1;    // pairs

    // prologue: stage pair 0 (tiles 0,1 = 8192 contiguous ushorts per array)
    #pragma unroll
    for (int i = 0; i < 2; i++) {
        GLD16(kbase + (size_t)(t + i * 512) * 8, &Ks[0][(t + i * 512) * 8]);
        GLD16(vbase + (size_t)(t + i * 512) * 8, &Vs[0][(t + i * 512) * 8]);
    }

    for (int st = 0; st < nsteps; st++) {
        const int cur = st & 1;
        __syncthreads();                      // pair(st) staged; other buf free
        if (st + 1 < nsteps) {                // prefetch next pair
            const ushort* kim = kbase + (size_t)(st + 1) * 8192;
            const ushort* vim = vbase + (size_t)(st + 1) * 8192;
            #pragma unroll
            for (int i = 0; i < 2; i++) {
                GLD16(kim + (size_t)(t + i * 512) * 8, &Ks[cur ^ 1][(t + i * 512) * 8]);
                GLD16(vim + (size_t)(t + i * 512) * 8, &Vs[cur ^ 1][(t + i * 512) * 8]);
            }
        }
        #pragma unroll
        for (int sub = 0; sub < 2; sub++) {
            const int kt = st * 2 + sub;
            if (kt < ntiles && kt <= myqT)
                attn_step(qf, Of, lpart,
                          &Ks[cur][sub * 4096], &Vs[cur][sub * 4096], pw,
                          kt * KVBLK, q0, (kt == myqT) ? 1 : 0, ws, l15, lg);
        }
    }

    #pragma unroll
    for (int j = 0; j < 4; j++) {
        float lsum = lpart[j];
        lsum += __shfl_xor(lsum, 1);
        lsum += __shfl_xor(lsum, 2);
        lsum += __shfl_xor(lsum, 4);
        lsum += __shfl_xor(lsum, 8);
        const float inv = 1.f / lsum;
        const int qg = q0 + ws * 16 + lg * 4 + j;
        #pragma unroll
        for (int df = 0; df < 4; df++)
            o[(size_t)qg * DMODEL + h * HEADD + df * 16 + l15] = f2bf(Of[df][j] * inv);
    }
}

// ===========================================================================
// Fallback f32 path (only if ws too small)
// ===========================================================================
__global__ void layernorm_k(const float* __restrict__ x,
                            const float* __restrict__ g,
                            const float* __restrict__ b,
                            float* __restrict__ y) {
    const int row = blockIdx.x;
    const float* xr = x + (size_t)row * DMODEL;
    __shared__ float red[256];
    const int tid = threadIdx.x;
    float s = 0.f;
    for (int d = tid; d < DMODEL; d += 256) s += xr[d];
    red[tid] = s; __syncthreads();
    for (int off = 128; off > 0; off >>= 1) {
        if (tid < off) red[tid] += red[tid + off];
        __syncthreads();
    }
    const float mu = red[0] / DMODEL;
    __syncthreads();
    float v = 0.f;
    for (int d = tid; d < DMODEL; d += 256) { float tv = xr[d] - mu; v += tv * tv; }
    red[tid] = v; __syncthreads();
    for (int off = 128; off > 0; off >>= 1) {
        if (tid < off) red[tid] += red[tid + off];
        __syncthreads();
    }
    const float rstd = rsqrtf(red[0] / DMODEL + 1e-5f);
    for (int d = tid; d < DMODEL; d += 256)
        y[(size_t)row * DMODEL + d] = (xr[d] - mu) * rstd * g[d] + b[d];
}

#define BM 64
#define BN 64
#define BK 16
__global__ __launch_bounds__(256)
void gemm_f32(const float* __restrict__ A, const float* __restrict__ B,
              const float* __restrict__ bias, const float* __restrict__ addsrc,
              float* __restrict__ C, int M, int N, int K, int act) {
    __shared__ float As[BK][BM];
    __shared__ float Bs[BK][BN];
    const int bm = blockIdx.y * BM;
    const int bn = blockIdx.x * BN;
    const int tid = threadIdx.x;
    const int tr = tid >> 4;
    const int tc = tid & 15;
    float acc[4][4] = {};
    for (int k0 = 0; k0 < K; k0 += BK) {
        #pragma unroll
        for (int i = 0; i < 4; i++) {
            int idx = tid + i * 256;
            int row = idx >> 4, col = idx & 15;
            int gm = bm + row;
            float v = 0.f;
            if (gm < M) v = A[(size_t)gm * K + (k0 + col)];
            As[col][row] = v;
        }
        #pragma unroll
        for (int i = 0; i < 4; i++) {
            int idx = tid + i * 256;
            int row = idx >> 6, col = idx & 63;
            int gn = bn + col;
            float v = 0.f;
            if (gn < N) v = B[(size_t)(k0 + row) * N + gn];
            Bs[row][col] = v;
        }
        __syncthreads();
        #pragma unroll
        for (int kk = 0; kk < BK; kk++) {
            float a[4], bb[4];
            #pragma unroll
            for (int i = 0; i < 4; i++) a[i] = As[kk][tr * 4 + i];
            #pragma unroll
            for (int j = 0; j < 4; j++) bb[j] = Bs[kk][tc * 4 + j];
            #pragma unroll
            for (int i = 0; i < 4; i++)
                #pragma unroll
                for (int j = 0; j < 4; j++)
                    acc[i][j] += a[i] * bb[j];
        }
        __syncthreads();
    }
    #pragma unroll
    for (int i = 0; i < 4; i++) {
        int gm = bm + tr * 4 + i;
        if (gm >= M) continue;
        #pragma unroll
        for (int j = 0; j < 4; j++) {
            int gn = bn + tc * 4 + j;
            if (gn >= N) continue;
            float v = acc[i][j] + (bias ? bias[gn] : 0.f);
            if (act == 1) {
                const float cst = 0.7978845608028654f;
                float tt = tanhf(cst * (v + 0.044715f * v * v * v));
                v = 0.5f * v * (1.f + tt);
            }
            if (addsrc) v += addsrc[(size_t)gm * N + gn];
            C[(size_t)gm * N + gn] = v;
        }
    }
}

__global__ __launch_bounds__(256)
void attn_k(const float* __restrict__ qkv, float* __restrict__ o) {
    const int q = blockIdx.x;
    const int h = blockIdx.y;
    const int tid = threadIdx.x;
    __shared__ float qrow[HEADD];
    __shared__ float sc[NCTX];
    __shared__ float red[256];
    __shared__ float part[4][HEADD];
    if (tid < HEADD) qrow[tid] = qkv[(size_t)q * D3 + h * HEADD + tid];
    __syncthreads();
    const float scale = 0.125f;
    float lmax = -1e30f;
    for (int k = tid; k <= q; k += 256) {
        const float* kr = qkv + (size_t)k * D3 + DMODEL + h * HEADD;
        float s = 0.f;
        #pragma unroll
        for (int d = 0; d < HEADD; d++) s += qrow[d] * kr[d];
        s *= scale;
        sc[k] = s;
        lmax = fmaxf(lmax, s);
    }
    red[tid] = lmax; __syncthreads();
    for (int off = 128; off > 0; off >>= 1) {
        if (tid < off) red[tid] = fmaxf(red[tid], red[tid + off]);
        __syncthreads();
    }
    const float m = red[0];
    __syncthreads();
    float lsum = 0.f;
    for (int k = tid; k <= q; k += 256) {
        float p = expf(sc[k] - m);
        sc[k] = p;
        lsum += p;
    }
    red[tid] = lsum; __syncthreads();
    for (int off = 128; off > 0; off >>= 1) {
        if (tid < off) red[tid] += red[tid + off];
        __syncthreads();
    }
    const float inv = 1.f / red[0];
    const int grp = tid >> 6;
    const int d = tid & 63;
    float acc = 0.f;
    for (int k = grp; k <= q; k += 4)
        acc += sc[k] * qkv[(size_t)k * D3 + 2 * DMODEL + h * HEADD + d];
    part[grp][d] = acc;
    __syncthreads();
    if (tid < HEADD) {
        float v = (part[0][tid] + part[1][tid] + part[2][tid] + part[3][tid]) * inv;
        o[(size_t)q * DMODEL + h * HEADD + tid] = v;
    }
}

// ---------------------------------------------------------------------------
// Launch
// ---------------------------------------------------------------------------
extern "C" void kernel_launch(void* const* d_in, const int* in_sizes, int n_in,
                              void* d_out, int out_size, void* d_ws, size_t ws_size,
                              hipStream_t stream) {
    const int*   tokens      = (const int*)  d_in[0];
    const float* vocab_embed = (const float*)d_in[1];
    const float* pos_embed   = (const float*)d_in[2];
    const float* ln1_g       = (const float*)d_in[3];
    const float* ln1_b       = (const float*)d_in[4];
    const float* att_w       = (const float*)d_in[5];
    const float* att_b       = (const float*)d_in[6];
    const float* attn_proj_w = (const float*)d_in[7];
    const float* attn_proj_b = (const float*)d_in[8];
    const float* ln2_g       = (const float*)d_in[9];
    const float* ln2_b       = (const float*)d_in[10];
    const float* fc_w        = (const float*)d_in[11];
    const float* fc_b        = (const float*)d_in[12];
    const float* mlp_proj_w  = (const float*)d_in[13];
    const float* mlp_proj_b  = (const float*)d_in[14];
    const float* lnf_g       = (const float*)d_in[15];
    const float* lnf_b       = (const float*)d_in[16];
    const float* out_w       = (const float*)d_in[17];
    const float* out_b       = (const float*)d_in[18];
    float* out = (float*)d_out;

    const int C = NCTX;
    dim3 blk(256);

    // ---- workspace carve for bf16 path ----
    char* wp = (char*)d_ws;
    size_t used = 0;
    auto carve = [&](size_t bytes) -> void* {
        bytes = (bytes + 255) & ~(size_t)255;
        void* p = wp + used;
        used += bytes;
        return p;
    };
    float*  x_f    = (float*) carve((size_t)C * DMODEL * 4);
    ushort* h_bf   = (ushort*)carve((size_t)C * DMODEL * 2);
    ushort* qkv_bf = (ushort*)carve((size_t)C * D3 * 2);
    ushort* o_bf   = (ushort*)carve((size_t)C * DMODEL * 2);
    ushort* mid_bf = (ushort*)carve((size_t)C * D4 * 2);
    ushort* wt_a   = (ushort*)carve((size_t)D3 * DMODEL * 2);
    ushort* wt_p   = (ushort*)carve((size_t)DMODEL * DMODEL * 2);
    ushort* wt_f   = (ushort*)carve((size_t)D4 * DMODEL * 2);
    ushort* wt_m   = (ushort*)carve((size_t)DMODEL * D4 * 2);
    ushort* wt_out = (ushort*)carve((size_t)NVPAD * DMODEL * 2);
    ushort* Kimg   = (ushort*)carve((size_t)NHEAD * (C / KVBLK) * 4096 * 2);
    ushort* Vimg   = (ushort*)carve((size_t)NHEAD * (C / KVBLK) * 4096 * 2);

    if (ws_size >= used) {
        // ================= bf16 MFMA path =================
        transp64<<<dim3(NVPAD / 64, DMODEL / 64), blk, 0, stream>>>(
            out_w, wt_out, DMODEL, NVOCAB);

        embed_k<<<dim3(C), blk, 0, stream>>>(tokens, vocab_embed, pos_embed, x_f);

        for (int l = 0; l < LAYERS; l++) {
            transp4<<<dim3(1728), blk, 0, stream>>>(
                att_w + (size_t)l * DMODEL * D3,
                attn_proj_w + (size_t)l * DMODEL * DMODEL,
                fc_w + (size_t)l * DMODEL * D4,
                mlp_proj_w + (size_t)l * D4 * DMODEL,
                wt_a, wt_p, wt_f, wt_m);

            ln_v2<<<dim3(C / 4), blk, 0, stream>>>(
                x_f, ln1_g + l * DMODEL, ln1_b + l * DMODEL, nullptr, h_bf);

            gemm3<128, 0, false, true><<<dim3(D3 / 128, C / 128), blk, 0, stream>>>(
                h_bf, wt_a, att_b + l * D3, nullptr, qkv_bf, D3, DMODEL);

            qkv_tiles_k<<<dim3(NHEAD, C / KVBLK), blk, 0, stream>>>(qkv_bf, Kimg, Vimg);

            attn_mfma2<<<dim3(NHEAD, 16), dim3(512), 0, stream>>>(qkv_bf, Kimg, Vimg, o_bf);

            gemm3<64, 0, true, false><<<dim3(DMODEL / 128, C / 64), blk, 0, stream>>>(
                o_bf, wt_p, attn_proj_b + l * DMODEL, h_bf, x_f, DMODEL, DMODEL);

            ln_v2<<<dim3(C / 4), blk, 0, stream>>>(
                x_f, ln2_g + l * DMODEL, ln2_b + l * DMODEL, nullptr, h_bf);

            gemm3<128, 1, false, true><<<dim3(D4 / 128, C / 128), blk, 0, stream>>>(
                h_bf, wt_f, fc_b + l * D4, nullptr, mid_bf, D4, DMODEL);

            gemm3<64, 0, true, false><<<dim3(DMODEL / 128, C / 64), blk, 0, stream>>>(
                mid_bf, wt_m, mlp_proj_b + l * DMODEL, h_bf, x_f, DMODEL, D4);
        }

        ln_v2<<<dim3(C / 4), blk, 0, stream>>>(x_f, lnf_g, lnf_b, nullptr, h_bf);

        gemm_logits<<<dim3(1576), dim3(1024), 0, stream>>>(h_bf, wt_out, out_b, out);
        return;
    }

    // ================= fallback f32 path =================
    const size_t n_x   = (size_t)C * DMODEL;
    const size_t n_qkv = (size_t)C * D3;
    const size_t need_bytes = (3 * n_x + n_qkv + (size_t)C * D4) * sizeof(float);

    float *x, *h, *o, *qkv, *mid;
    float* ws = (float*)d_ws;
    if (ws_size >= need_bytes) {
        x = ws; h = x + n_x; o = h + n_x; qkv = o + n_x; mid = qkv + n_qkv;
    } else {
        x = ws; h = x + n_x; o = h + n_x;
        qkv = (float*)d_out; mid = qkv + n_qkv;
    }

    embed_k<<<dim3(C), blk, 0, stream>>>(tokens, vocab_embed, pos_embed, x);
    for (int l = 0; l < LAYERS; l++) {
        const float* lw;
        layernorm_k<<<dim3(C), blk, 0, stream>>>(x, ln1_g + l * DMODEL, ln1_b + l * DMODEL, h);
        lw = att_w + (size_t)l * DMODEL * D3;
        gemm_f32<<<dim3(D3 / BN, C / BM), blk, 0, stream>>>(
            h, lw, att_b + l * D3, nullptr, qkv, C, D3, DMODEL, 0);
        attn_k<<<dim3(C, NHEAD), blk, 0, stream>>>(qkv, o);
        lw = attn_proj_w + (size_t)l * DMODEL * DMODEL;
        gemm_f32<<<dim3(DMODEL / BN, C / BM), blk, 0, stream>>>(
            o, lw, attn_proj_b + l * DMODEL, h, x, C, DMODEL, DMODEL, 0);
        layernorm_k<<<dim3(C), blk, 0, stream>>>(x, ln2_g + l * DMODEL, ln2_b + l * DMODEL, h);
        lw = fc_w + (size_t)l * DMODEL * D4;
        gemm_f32<<<dim3(D4 / BN, C / BM), blk, 0, stream>>>(
            h, lw, fc_b + l * D4, nullptr, mid, C, D4, DMODEL, 1);
        lw = mlp_proj_w + (size_t)l * D4 * DMODEL;
        gemm_f32<<<dim3(DMODEL / BN, C / BM), blk, 0, stream>>>(
            mid, lw, mlp_proj_b + l * DMODEL, h, x, C, DMODEL, D4, 0);
    }
    layernorm_k<<<dim3(C), blk, 0, stream>>>(x, lnf_g, lnf_b, h);
    gemm_f32<<<dim3((NVOCAB + BN - 1) / BN, C / BM), blk, 0, stream>>>(
        h, out_w, out_b, nullptr, out, C, NVOCAB, DMODEL, 0);
}

// Round 23
// 872.571 us; speedup vs baseline: 1.0580x; 1.0091x over previous
//
#include <hip/hip_runtime.h>
#include <hip/hip_bf16.h>
#include <math.h>

// Problem constants
#define LAYERS 4
#define NHEAD  12
#define DMODEL 768
#define HEADD  64
#define NCTX   2048
#define NVOCAB 50257
#define NVPAD  50432            // 788*64 = 197*256
#define D3     (3*DMODEL)
#define D4     (4*DMODEL)

typedef short short8 __attribute__((ext_vector_type(8)));
typedef float f32x4  __attribute__((ext_vector_type(4)));
typedef float f32x4u __attribute__((ext_vector_type(4), aligned(4)));
typedef ushort ushx4 __attribute__((ext_vector_type(4)));

__device__ __forceinline__ float bf2f(ushort u) {
    union { uint i; float f; } c; c.i = ((uint)u) << 16; return c.f;
}
__device__ __forceinline__ ushort f2bf(float f) {
    union { float f; uint i; } c; c.f = f;
    uint i = c.i;
    uint r = (i + 0x7FFFu + ((i >> 16) & 1u)) >> 16;   // round-nearest-even
    return (ushort)r;
}

#define GLD16(gp, lp) __builtin_amdgcn_global_load_lds( \
    (__attribute__((address_space(1))) void*)(gp),      \
    (__attribute__((address_space(3))) void*)(lp), 16, 0, 0)

// vmcnt-only wait + raw barrier (no lgkmcnt drain)
#define BARS() do { asm volatile("s_waitcnt vmcnt(0)" ::: "memory"); \
                    __builtin_amdgcn_s_barrier(); } while (0)

// ---------------------------------------------------------------------------
// Embedding
// ---------------------------------------------------------------------------
__global__ void embed_k(const int* __restrict__ tok,
                        const float* __restrict__ ve,
                        const float* __restrict__ pe,
                        float* __restrict__ x) {
    int c = blockIdx.x;
    int t = tok[c];
    for (int d = threadIdx.x; d < DMODEL; d += blockDim.x)
        x[(size_t)c * DMODEL + d] = ve[(size_t)t * DMODEL + d] + pe[(size_t)c * DMODEL + d];
}

// ---------------------------------------------------------------------------
// LayerNorm: one wave per row, single pass, shuffle-only.
// ---------------------------------------------------------------------------
__global__ __launch_bounds__(256) void ln_v2(const float* __restrict__ x,
                                             const float* __restrict__ g,
                                             const float* __restrict__ b,
                                             float* __restrict__ yf,
                                             ushort* __restrict__ ybf) {
    const int w = threadIdx.x >> 6, l = threadIdx.x & 63;
    const int row = blockIdx.x * 4 + w;
    const float* xr = x + (size_t)row * DMODEL;

    f32x4 v[3];
    float s = 0.f, ss = 0.f;
    #pragma unroll
    for (int i = 0; i < 3; i++) {
        v[i] = *(const f32x4*)(xr + (l + 64 * i) * 4);
        #pragma unroll
        for (int k = 0; k < 4; k++) { s += v[i][k]; ss += v[i][k] * v[i][k]; }
    }
    #pragma unroll
    for (int off = 32; off > 0; off >>= 1) {
        s  += __shfl_xor(s, off);
        ss += __shfl_xor(ss, off);
    }
    const float mu = s * (1.f / DMODEL);
    const float var = ss * (1.f / DMODEL) - mu * mu;
    const float rstd = rsqrtf(var + 1e-5f);

    #pragma unroll
    for (int i = 0; i < 3; i++) {
        const int idx = l + 64 * i;
        f32x4 g4 = *(const f32x4*)(g + idx * 4);
        f32x4 b4 = *(const f32x4*)(b + idx * 4);
        f32x4 r;
        #pragma unroll
        for (int k = 0; k < 4; k++) r[k] = (v[i][k] - mu) * rstd * g4[k] + b4[k];
        if (yf) *(f32x4*)(yf + (size_t)row * DMODEL + idx * 4) = r;
        if (ybf) {
            ushx4 u;
            #pragma unroll
            for (int k = 0; k < 4; k++) u[k] = f2bf(r[k]);
            *(ushx4*)(ybf + (size_t)row * DMODEL + idx * 4) = u;
        }
    }
}

// ---------------------------------------------------------------------------
// Transpose + f32->bf16, 64x64 tiles, coalesced lane mapping.
// ---------------------------------------------------------------------------
__device__ __forceinline__ void transp64_body(const float* __restrict__ src,
                                              ushort* __restrict__ dst,
                                              int K, int N, int nt, int kt) {
    __shared__ float tile[64][65];
    const int t = threadIdx.x;

    {
        const int r0 = t >> 4;          // 0..15
        const int c  = (t & 15) * 4;    // 0..60
        #pragma unroll
        for (int i = 0; i < 4; i++) {
            const int r = r0 + i * 16;
            const int n = nt + c;
            const float* srow = src + (size_t)(kt + r) * N;
            f32x4 v;
            if (n + 3 < N) {
                v = *(const f32x4u*)(srow + n);
            } else {
                #pragma unroll
                for (int e = 0; e < 4; e++)
                    v[e] = (n + e < N) ? srow[n + e] : 0.f;
            }
            #pragma unroll
            for (int e = 0; e < 4; e++) tile[r][c + e] = v[e];
        }
    }
    __syncthreads();
    {
        const int nl0 = t >> 3;         // 0..31
        const int kb  = (t & 7) * 8;    // 0..56
        #pragma unroll
        for (int h = 0; h < 2; h++) {
            const int nl = nl0 + h * 32;
            short8 o;
            #pragma unroll
            for (int j = 0; j < 8; j++)
                o[j] = (short)f2bf(tile[kb + j][nl]);
            *(short8*)(dst + (size_t)(nt + nl) * K + kt + kb) = o;
        }
    }
}

__global__ __launch_bounds__(256) void transp64(const float* __restrict__ src,
                                                ushort* __restrict__ dst,
                                                int K, int N) {
    transp64_body(src, dst, K, N, blockIdx.x * 64, blockIdx.y * 64);
}

// ---------------------------------------------------------------------------
// Fused per-layer weight transposes. Grid 1728 = 432 + 144 + 576 + 576.
// ---------------------------------------------------------------------------
__global__ __launch_bounds__(256) void transp4(
    const float* __restrict__ s0, const float* __restrict__ s1,
    const float* __restrict__ s2, const float* __restrict__ s3,
    ushort* __restrict__ d0, ushort* __restrict__ d1,
    ushort* __restrict__ d2, ushort* __restrict__ d3)
{
    const int bid = blockIdx.x;
    const float* src; ushort* dst; int K, N, nx, tb;
    if (bid < 432)       { src = s0; dst = d0; K = 768;  N = 2304; nx = 36; tb = bid; }
    else if (bid < 576)  { src = s1; dst = d1; K = 768;  N = 768;  nx = 12; tb = bid - 432; }
    else if (bid < 1152) { src = s2; dst = d2; K = 768;  N = 3072; nx = 48; tb = bid - 576; }
    else                 { src = s3; dst = d3; K = 3072; N = 768;  nx = 12; tb = bid - 1152; }
    transp64_body(src, dst, K, N, (tb % nx) * 64, (tb / nx) * 64);
}

// ===========================================================================
// Layer GEMM v3: counted-vmcnt 3-buffer pipeline. 256 thr, MTx128, BK=32.
// HASADD residual source is bf16.
// ===========================================================================
template<int MT, int ACT, bool HASADD, bool OUTBF>
__global__ __launch_bounds__(256) void gemm3(
    const ushort* __restrict__ A, const ushort* __restrict__ Bt,
    const float* __restrict__ bias, const ushort* __restrict__ addsrc,
    void* __restrict__ Cout, int N, int K)
{
    constexpr int AFR  = MT / 32;
    constexpr int ABYT = MT * 64;
    constexpr int BUF  = ABYT + 8192;
    constexpr int LPS  = MT / 64 + 2;
    __shared__ __align__(16) char smem[3 * BUF];
    const int bm = blockIdx.y * MT, bn = blockIdx.x * 128;
    const int t = threadIdx.x, l = t & 63, w = t >> 6;
    const int wrb = (w >> 1) * (MT / 2), wcb = (w & 1) * 64;
    const int l15 = l & 15, lg = l >> 4;
    const int swr = ((l15 >> 1) & 3) << 4;

    const int srow = t >> 2;
    const int ssc  = ((t & 3) ^ ((srow >> 1) & 3)) * 8;
    const ushort* Abase = A  + (size_t)(bm + srow) * K + ssc;
    const ushort* Bbase = Bt + (size_t)(bn + srow) * K + ssc;

    f32x4 acc[AFR][4];
    #pragma unroll
    for (int i = 0; i < AFR; i++)
        #pragma unroll
        for (int j = 0; j < 4; j++) acc[i][j] = (f32x4)0.f;

    auto STAGE = [&](int buf, int ke) {
        ushort* as = (ushort*)(smem + buf * BUF);
        ushort* bs = (ushort*)(smem + buf * BUF + ABYT);
        #pragma unroll
        for (int i = 0; i < MT / 64; i++)
            GLD16(Abase + (size_t)i * 64 * K + ke, as + (t + i * 256) * 8);
        #pragma unroll
        for (int i = 0; i < 2; i++)
            GLD16(Bbase + (size_t)i * 64 * K + ke, bs + (t + i * 256) * 8);
    };
    auto COMPUTE = [&](int buf) {
        const char* as = smem + buf * BUF;
        const char* bs = smem + buf * BUF + ABYT;
        short8 af[AFR], bfr[4];
        #pragma unroll
        for (int f = 0; f < AFR; f++)
            af[f] = *(const short8*)(as + (((wrb + f * 16 + l15) * 64 + lg * 16) ^ swr));
        #pragma unroll
        for (int f = 0; f < 4; f++)
            bfr[f] = *(const short8*)(bs + (((wcb + f * 16 + l15) * 64 + lg * 16) ^ swr));
        __builtin_amdgcn_s_setprio(1);
        #pragma unroll
        for (int fm = 0; fm < AFR; fm++)
            #pragma unroll
            for (int fn = 0; fn < 4; fn++)
                acc[fm][fn] = __builtin_amdgcn_mfma_f32_16x16x32_bf16(
                    af[fm], bfr[fn], acc[fm][fn], 0, 0, 0);
        __builtin_amdgcn_s_setprio(0);
    };

    const int nk = K >> 5;
    STAGE(0, 0);
    STAGE(1, 32);
    int bc = 0, bs2 = 2;                      // compute buf, stage buf
    for (int kt = 0; kt < nk; kt++) {
        if (kt < nk - 1)
            asm volatile("s_waitcnt vmcnt(%0)" :: "i"(LPS) : "memory");
        else
            asm volatile("s_waitcnt vmcnt(0)" ::: "memory");
        __builtin_amdgcn_s_barrier();
        asm volatile("" ::: "memory");
        if (kt + 2 < nk) STAGE(bs2, (kt + 2) << 5);
        COMPUTE(bc);
        bc  = (bc  == 2) ? 0 : bc  + 1;
        bs2 = (bs2 == 2) ? 0 : bs2 + 1;
    }

    #pragma unroll
    for (int fn = 0; fn < 4; fn++) {
        const int col = bn + wcb + fn * 16 + l15;
        const float bi = bias[col];
        #pragma unroll
        for (int fm = 0; fm < AFR; fm++) {
            #pragma unroll
            for (int j = 0; j < 4; j++) {
                const int row = bm + wrb + fm * 16 + lg * 4 + j;
                float v = acc[fm][fn][j] + bi;
                if (ACT == 1) {
                    float u = 0.7978845608028654f * (v + 0.044715f * v * v * v);
                    v = 0.5f * v * (1.f + tanhf(u));
                }
                if (HASADD) v += bf2f(addsrc[(size_t)row * N + col]);
                if (OUTBF) ((ushort*)Cout)[(size_t)row * N + col] = f2bf(v);
                else       ((float*) Cout)[(size_t)row * N + col] = v;
            }
        }
    }
}

// ---------------------------------------------------------------------------
// Logits GEMM: 256x256 tile, 1024 threads (16 waves, 4M x 4N), BK=32.
// 3-buffer counted-vmcnt pipeline (96 KB LDS, 4 waves/SIMD).
// XCD-chunked bijective mapping over 1576 = 8*197 blocks.
// 4-pass LDS-staged f32 epilogue (contiguous coalesced rows).
// ---------------------------------------------------------------------------
__global__ __launch_bounds__(1024) void gemm_logits(
    const ushort* __restrict__ A, const ushort* __restrict__ Bt,
    const float* __restrict__ bias, float* __restrict__ Cout)
{
    __shared__ __align__(16) char smem[98304];   // 3 x (16 KB A + 16 KB B)
    float* Cs = (float*)smem;                     // epilogue: 64 x 256 f32

    const int pid = (blockIdx.x & 7) * 197 + (blockIdx.x >> 3);
    const int np = pid >> 3, mt = pid & 7;
    const int bm = mt * 256, bn = np * 256;
    const int t = threadIdx.x, l = t & 63, w = t >> 6;   // w 0..15
    const int wm = w >> 2, wn = w & 3;          // 4 x 4 wave grid
    const int l15 = l & 15, lg = l >> 4;
    const int swr = ((l15 >> 1) & 3) << 4;

    const int sr  = t >> 2;                     // 0..255
    const int ssc = ((t & 3) ^ ((sr >> 1) & 3)) * 8;
    const ushort* Ab = A  + (size_t)(bm + sr) * DMODEL + ssc;
    const ushort* Bb = Bt + (size_t)(bn + sr) * DMODEL + ssc;

    f32x4 acc[4][4];
    #pragma unroll
    for (int i = 0; i < 4; i++)
        #pragma unroll
        for (int j = 0; j < 4; j++) acc[i][j] = (f32x4)0.f;

    auto STAGE = [&](int buf, int ke) {
        ushort* as = (ushort*)(smem + buf * 32768);
        ushort* bs = (ushort*)(smem + buf * 32768 + 16384);
        GLD16(Ab + ke, as + t * 8);
        GLD16(Bb + ke, bs + t * 8);
    };
    auto COMPUTE = [&](int buf) {
        const char* as = smem + buf * 32768;
        const char* bs = smem + buf * 32768 + 16384;
        short8 bfr[4];
        #pragma unroll
        for (int f = 0; f < 4; f++) {
            const int r = wn * 64 + f * 16 + l15;
            bfr[f] = *(const short8*)(bs + ((r * 64 + lg * 16) ^ swr));
        }
        __builtin_amdgcn_s_setprio(1);
        #pragma unroll
        for (int fm = 0; fm < 4; fm++) {
            const int r = wm * 64 + fm * 16 + l15;
            short8 af = *(const short8*)(as + ((r * 64 + lg * 16) ^ swr));
            #pragma unroll
            for (int fn = 0; fn < 4; fn++)
                acc[fm][fn] = __builtin_amdgcn_mfma_f32_16x16x32_bf16(
                    af, bfr[fn], acc[fm][fn], 0, 0, 0);
        }
        __builtin_amdgcn_s_setprio(0);
    };

    STAGE(0, 0);
    STAGE(1, 32);
    #pragma unroll
    for (int kt = 0; kt < 24; kt++) {
        if (kt <= 22) asm volatile("s_waitcnt vmcnt(2)" ::: "memory");
        else          asm volatile("s_waitcnt vmcnt(0)" ::: "memory");
        __builtin_amdgcn_s_barrier();
        asm volatile("" ::: "memory");
        if (kt + 2 < 24) STAGE((kt + 2) % 3, (kt + 2) * 32);
        COMPUTE(kt % 3);
    }

    // Epilogue: 4 passes of 64 rows via LDS (first 64 KB of smem).
    #pragma unroll
    for (int p = 0; p < 4; p++) {
        __syncthreads();
        if (wm == p) {
            #pragma unroll
            for (int fm = 0; fm < 4; fm++) {
                #pragma unroll
                for (int fn = 0; fn < 4; fn++) {
                    const int ccol = wn * 64 + fn * 16 + l15;
                    const int gcol = bn + ccol;
                    const float bi = (gcol < NVOCAB) ? bias[gcol] : 0.f;
                    #pragma unroll
                    for (int j = 0; j < 4; j++)
                        Cs[(fm * 16 + lg * 4 + j) * 256 + ccol] = acc[fm][fn][j] + bi;
                }
            }
        }
        __syncthreads();
        const int grow0 = bm + p * 64;
        #pragma unroll
        for (int i = 0; i < 4; i++) {
            const int idx = t + i * 1024;
            const int rr = idx >> 6, ch = idx & 63;
            f32x4 v = *(const f32x4*)(Cs + rr * 256 + ch * 4);
            float* dst = Cout + (size_t)(grow0 + rr) * NVOCAB + bn + ch * 4;
            if (bn + 256 <= NVOCAB) {
                *(f32x4u*)dst = v;
            } else {
                #pragma unroll
                for (int e = 0; e < 4; e++)
                    if (bn + ch * 4 + e < NVOCAB) dst[e] = v[e];
            }
        }
    }
}

// ---------------------------------------------------------------------------
// Build per-(head, kv-tile) swizzled K and V^T tile images (8 KB each).
// ---------------------------------------------------------------------------
#define QBLK  64
#define KVBLK 64
__global__ __launch_bounds__(256) void qkv_tiles_k(const ushort* __restrict__ qkv,
                                                   ushort* __restrict__ Kimg,
                                                   ushort* __restrict__ Vimg) {
    __shared__ __align__(16) ushort Vt_l[4096];
    const int h = blockIdx.x;
    const int kt = blockIdx.y;
    const int k0 = kt * KVBLK;
    const int t = threadIdx.x;
    ushort* kd = Kimg + ((size_t)h * (NCTX / KVBLK) + kt) * 4096;
    ushort* vd = Vimg + ((size_t)h * (NCTX / KVBLK) + kt) * 4096;

    #pragma unroll
    for (int i = 0; i < 2; i++) {
        const int c = t + i * 256;
        const int r = c >> 3, cc = c & 7;
        short8 kv8 = *(const short8*)(qkv + (size_t)(k0 + r) * D3 + DMODEL + h * HEADD + cc * 8);
        *(short8*)(kd + (((r * 8 + cc) ^ (r & 7)) * 8)) = kv8;
        short8 vv = *(const short8*)(qkv + (size_t)(k0 + r) * D3 + 2 * DMODEL + h * HEADD + cc * 8);
        #pragma unroll
        for (int j = 0; j < 8; j++) {
            const int d = cc * 8 + j;
            const int addr = (d * 128 + r * 2) ^ ((d & 7) << 4);
            *(ushort*)((char*)Vt_l + addr) = (ushort)vv[j];
        }
    }
    __syncthreads();
    #pragma unroll
    for (int i = 0; i < 2; i++) {
        const int c = t + i * 256;
        *(short8*)(vd + c * 8) = *(const short8*)(Vt_l + c * 8);
    }
}

// ---------------------------------------------------------------------------
// One attention stream step, NO-MAX softmax variant.
// ---------------------------------------------------------------------------
__device__ __forceinline__ void attn_step(
    const short8 qf[2], f32x4 Of[4], float lpart[4],
    const ushort* Kt, const ushort* Vt, char* pw,
    int k0, int q0, int maskTile, int w, int l15, int lg)
{
    const float scale = 0.125f;
    f32x4 S[4];
    __builtin_amdgcn_s_setprio(1);
    #pragma unroll
    for (int nf = 0; nf < 4; nf++) {
        f32x4 a = (f32x4)0.f;
        #pragma unroll
        for (int s = 0; s < 2; s++) {
            const int r = nf * 16 + l15;
            const int addr = (r * 128 + s * 64 + lg * 16) ^ ((r & 7) << 4);
            short8 kf = *(const short8*)((const char*)Kt + addr);
            a = __builtin_amdgcn_mfma_f32_16x16x32_bf16(qf[s], kf, a, 0, 0, 0);
        }
        S[nf] = a;
    }
    __builtin_amdgcn_s_setprio(0);

    float p[4][4];
    if (maskTile) {
        #pragma unroll
        for (int nf = 0; nf < 4; nf++) {
            const int kvg = k0 + nf * 16 + l15;
            #pragma unroll
            for (int j = 0; j < 4; j++) {
                const int qg = q0 + w * 16 + lg * 4 + j;
                p[nf][j] = (kvg <= qg) ? __expf(S[nf][j] * scale) : 0.f;
            }
        }
    } else {
        #pragma unroll
        for (int nf = 0; nf < 4; nf++)
            #pragma unroll
            for (int j = 0; j < 4; j++)
                p[nf][j] = __expf(S[nf][j] * scale);
    }

    #pragma unroll
    for (int j = 0; j < 4; j++)
        lpart[j] += (p[0][j] + p[1][j]) + (p[2][j] + p[3][j]);

    #pragma unroll
    for (int nf = 0; nf < 4; nf++)
        #pragma unroll
        for (int j = 0; j < 4; j++) {
            const int ql = lg * 4 + j;
            const int addr = (ql * 128 + (nf * 16 + l15) * 2) ^ ((ql & 7) << 4);
            *(ushort*)(pw + addr) = f2bf(p[nf][j]);
        }

    __builtin_amdgcn_s_setprio(1);
    #pragma unroll
    for (int s = 0; s < 2; s++) {
        const int paddr = (l15 * 128 + s * 64 + lg * 16) ^ ((l15 & 7) << 4);
        short8 pf = *(const short8*)(pw + paddr);
        #pragma unroll
        for (int df = 0; df < 4; df++) {
            const int r = df * 16 + l15;
            const int vaddr = (r * 128 + s * 64 + lg * 16) ^ ((r & 7) << 4);
            short8 vf = *(const short8*)((const char*)Vt + vaddr);
            Of[df] = __builtin_amdgcn_mfma_f32_16x16x32_bf16(pf, vf, Of[df], 0, 0, 0);
        }
    }
    __builtin_amdgcn_s_setprio(0);
}

// ---------------------------------------------------------------------------
// MFMA flash attention, 8 waves, stream-split, QUAD KV tiles:
// four 64-col tiles staged per barrier period (32 KB contiguous per array),
// attn_step per sub-tile. Quarters barrier count; prefetch covered by 4x
// compute. LDS 144 KB (1 block/CU; grid 192 so residency unchanged).
// ---------------------------------------------------------------------------
__global__ __launch_bounds__(512) void attn_mfma2(const ushort* __restrict__ qkv,
                                                  const ushort* __restrict__ Kimg,
                                                  const ushort* __restrict__ Vimg,
                                                  ushort* __restrict__ o) {
    const int h   = blockIdx.x;
    const int qaT = blockIdx.y;          // 0..15
    const int qbT = 31 - qaT;            // 16..31
    const int t = threadIdx.x;
    const int w = t >> 6;                // 0..7
    const int strm = w >> 2;             // 0 = A (short), 1 = B (long)
    const int ws = w & 3;                // row-group within stream
    const int l = t & 63;
    const int l15 = l & 15, lg = l >> 4;

    __shared__ __align__(16) ushort Ks[2][16384];  // 2 x quad of 64-tiles
    __shared__ __align__(16) ushort Vs[2][16384];
    __shared__ __align__(16) ushort Ps[8][1024];

    const int myqT = strm ? qbT : qaT;
    const int q0 = myqT * QBLK;
    const ushort* kbase = Kimg + (size_t)h * (NCTX / KVBLK) * 4096;
    const ushort* vbase = Vimg + (size_t)h * (NCTX / KVBLK) * 4096;
    char* pw = (char*)&Ps[w][0];

    short8 qf[2];
    {
        const int qr = q0 + ws * 16 + l15;
        #pragma unroll
        for (int s = 0; s < 2; s++)
            qf[s] = *(const short8*)(qkv + (size_t)qr * D3 + h * HEADD + s * 32 + lg * 8);
    }

    f32x4 Of[4];
    float lpart[4];
    #pragma unroll
    for (int i = 0; i < 4; i++) {
        Of[i] = (f32x4)0.f;
        lpart[i] = 0.f;
    }

    const int ntiles = qbT + 1;              // 17..32 (64-col tiles)
    const int nsteps = (ntiles + 3) >> 2;    // quads (<= 8)

    // prologue: stage quad 0 (tiles 0-3 = 16384 contiguous ushorts per array)
    #pragma unroll
    for (int i = 0; i < 4; i++) {
        GLD16(kbase + (size_t)(t + i * 512) * 8, &Ks[0][(t + i * 512) * 8]);
        GLD16(vbase + (size_t)(t + i * 512) * 8, &Vs[0][(t + i * 512) * 8]);
    }

    for (int st = 0; st < nsteps; st++) {
        const int cur = st & 1;
        __syncthreads();                      // quad(st) staged; other buf free
        if (st + 1 < nsteps) {                // prefetch next quad
            const ushort* kim = kbase + (size_t)(st + 1) * 16384;
            const ushort* vim = vbase + (size_t)(st + 1) * 16384;
            #pragma unroll
            for (int i = 0; i < 4; i++) {
                GLD16(kim + (size_t)(t + i * 512) * 8, &Ks[cur ^ 1][(t + i * 512) * 8]);
                GLD16(vim + (size_t)(t + i * 512) * 8, &Vs[cur ^ 1][(t + i * 512) * 8]);
            }
        }
        #pragma unroll
        for (int sub = 0; sub < 4; sub++) {
            const int kt = st * 4 + sub;
            if (kt < ntiles && kt <= myqT)
                attn_step(qf, Of, lpart,
                          &Ks[cur][sub * 4096], &Vs[cur][sub * 4096], pw,
                          kt * KVBLK, q0, (kt == myqT) ? 1 : 0, ws, l15, lg);
        }
    }

    #pragma unroll
    for (int j = 0; j < 4; j++) {
        float lsum = lpart[j];
        lsum += __shfl_xor(lsum, 1);
        lsum += __shfl_xor(lsum, 2);
        lsum += __shfl_xor(lsum, 4);
        lsum += __shfl_xor(lsum, 8);
        const float inv = 1.f / lsum;
        const int qg = q0 + ws * 16 + lg * 4 + j;
        #pragma unroll
        for (int df = 0; df < 4; df++)
            o[(size_t)qg * DMODEL + h * HEADD + df * 16 + l15] = f2bf(Of[df][j] * inv);
    }
}

// ===========================================================================
// Fallback f32 path (only if ws too small)
// ===========================================================================
__global__ void layernorm_k(const float* __restrict__ x,
                            const float* __restrict__ g,
                            const float* __restrict__ b,
                            float* __restrict__ y) {
    const int row = blockIdx.x;
    const float* xr = x + (size_t)row * DMODEL;
    __shared__ float red[256];
    const int tid = threadIdx.x;
    float s = 0.f;
    for (int d = tid; d < DMODEL; d += 256) s += xr[d];
    red[tid] = s; __syncthreads();
    for (int off = 128; off > 0; off >>= 1) {
        if (tid < off) red[tid] += red[tid + off];
        __syncthreads();
    }
    const float mu = red[0] / DMODEL;
    __syncthreads();
    float v = 0.f;
    for (int d = tid; d < DMODEL; d += 256) { float tv = xr[d] - mu; v += tv * tv; }
    red[tid] = v; __syncthreads();
    for (int off = 128; off > 0; off >>= 1) {
        if (tid < off) red[tid] += red[tid + off];
        __syncthreads();
    }
    const float rstd = rsqrtf(red[0] / DMODEL + 1e-5f);
    for (int d = tid; d < DMODEL; d += 256)
        y[(size_t)row * DMODEL + d] = (xr[d] - mu) * rstd * g[d] + b[d];
}

#define BM 64
#define BN 64
#define BK 16
__global__ __launch_bounds__(256)
void gemm_f32(const float* __restrict__ A, const float* __restrict__ B,
              const float* __restrict__ bias, const float* __restrict__ addsrc,
              float* __restrict__ C, int M, int N, int K, int act) {
    __shared__ float As[BK][BM];
    __shared__ float Bs[BK][BN];
    const int bm = blockIdx.y * BM;
    const int bn = blockIdx.x * BN;
    const int tid = threadIdx.x;
    const int tr = tid >> 4;
    const int tc = tid & 15;
    float acc[4][4] = {};
    for (int k0 = 0; k0 < K; k0 += BK) {
        #pragma unroll
        for (int i = 0; i < 4; i++) {
            int idx = tid + i * 256;
            int row = idx >> 4, col = idx & 15;
            int gm = bm + row;
            float v = 0.f;
            if (gm < M) v = A[(size_t)gm * K + (k0 + col)];
            As[col][row] = v;
        }
        #pragma unroll
        for (int i = 0; i < 4; i++) {
            int idx = tid + i * 256;
            int row = idx >> 6, col = idx & 63;
            int gn = bn + col;
            float v = 0.f;
            if (gn < N) v = B[(size_t)(k0 + row) * N + gn];
            Bs[row][col] = v;
        }
        __syncthreads();
        #pragma unroll
        for (int kk = 0; kk < BK; kk++) {
            float a[4], bb[4];
            #pragma unroll
            for (int i = 0; i < 4; i++) a[i] = As[kk][tr * 4 + i];
            #pragma unroll
            for (int j = 0; j < 4; j++) bb[j] = Bs[kk][tc * 4 + j];
            #pragma unroll
            for (int i = 0; i < 4; i++)
                #pragma unroll
                for (int j = 0; j < 4; j++)
                    acc[i][j] += a[i] * bb[j];
        }
        __syncthreads();
    }
    #pragma unroll
    for (int i = 0; i < 4; i++) {
        int gm = bm + tr * 4 + i;
        if (gm >= M) continue;
        #pragma unroll
        for (int j = 0; j < 4; j++) {
            int gn = bn + tc * 4 + j;
            if (gn >= N) continue;
            float v = acc[i][j] + (bias ? bias[gn] : 0.f);
            if (act == 1) {
                const float cst = 0.7978845608028654f;
                float tt = tanhf(cst * (v + 0.044715f * v * v * v));
                v = 0.5f * v * (1.f + tt);
            }
            if (addsrc) v += addsrc[(size_t)gm * N + gn];
            C[(size_t)gm * N + gn] = v;
        }
    }
}

__global__ __launch_bounds__(256)
void attn_k(const float* __restrict__ qkv, float* __restrict__ o) {
    const int q = blockIdx.x;
    const int h = blockIdx.y;
    const int tid = threadIdx.x;
    __shared__ float qrow[HEADD];
    __shared__ float sc[NCTX];
    __shared__ float red[256];
    __shared__ float part[4][HEADD];
    if (tid < HEADD) qrow[tid] = qkv[(size_t)q * D3 + h * HEADD + tid];
    __syncthreads();
    const float scale = 0.125f;
    float lmax = -1e30f;
    for (int k = tid; k <= q; k += 256) {
        const float* kr = qkv + (size_t)k * D3 + DMODEL + h * HEADD;
        float s = 0.f;
        #pragma unroll
        for (int d = 0; d < HEADD; d++) s += qrow[d] * kr[d];
        s *= scale;
        sc[k] = s;
        lmax = fmaxf(lmax, s);
    }
    red[tid] = lmax; __syncthreads();
    for (int off = 128; off > 0; off >>= 1) {
        if (tid < off) red[tid] = fmaxf(red[tid], red[tid + off]);
        __syncthreads();
    }
    const float m = red[0];
    __syncthreads();
    float lsum = 0.f;
    for (int k = tid; k <= q; k += 256) {
        float p = expf(sc[k] - m);
        sc[k] = p;
        lsum += p;
    }
    red[tid] = lsum; __syncthreads();
    for (int off = 128; off > 0; off >>= 1) {
        if (tid < off) red[tid] += red[tid + off];
        __syncthreads();
    }
    const float inv = 1.f / red[0];
    const int grp = tid >> 6;
    const int d = tid & 63;
    float acc = 0.f;
    for (int k = grp; k <= q; k += 4)
        acc += sc[k] * qkv[(size_t)k * D3 + 2 * DMODEL + h * HEADD + d];
    part[grp][d] = acc;
    __syncthreads();
    if (tid < HEADD) {
        float v = (part[0][tid] + part[1][tid] + part[2][tid] + part[3][tid]) * inv;
        o[(size_t)q * DMODEL + h * HEADD + tid] = v;
    }
}

// ---------------------------------------------------------------------------
// Launch
// ---------------------------------------------------------------------------
extern "C" void kernel_launch(void* const* d_in, const int* in_sizes, int n_in,
                              void* d_out, int out_size, void* d_ws, size_t ws_size,
                              hipStream_t stream) {
    const int*   tokens      = (const int*)  d_in[0];
    const float* vocab_embed = (const float*)d_in[1];
    const float* pos_embed   = (const float*)d_in[2];
    const float* ln1_g       = (const float*)d_in[3];
    const float* ln1_b       = (const float*)d_in[4];
    const float* att_w       = (const float*)d_in[5];
    const float* att_b       = (const float*)d_in[6];
    const float* attn_proj_w = (const float*)d_in[7];
    const float* attn_proj_b = (const float*)d_in[8];
    const float* ln2_g       = (const float*)d_in[9];
    const float* ln2_b       = (const float*)d_in[10];
    const float* fc_w        = (const float*)d_in[11];
    const float* fc_b        = (const float*)d_in[12];
    const float* mlp_proj_w  = (const float*)d_in[13];
    const float* mlp_proj_b  = (const float*)d_in[14];
    const float* lnf_g       = (const float*)d_in[15];
    const float* lnf_b       = (const float*)d_in[16];
    const float* out_w       = (const float*)d_in[17];
    const float* out_b       = (const float*)d_in[18];
    float* out = (float*)d_out;

    const int C = NCTX;
    dim3 blk(256);

    // ---- workspace carve for bf16 path ----
    char* wp = (char*)d_ws;
    size_t used = 0;
    auto carve = [&](size_t bytes) -> void* {
        bytes = (bytes + 255) & ~(size_t)255;
        void* p = wp + used;
        used += bytes;
        return p;
    };
    float*  x_f    = (float*) carve((size_t)C * DMODEL * 4);
    ushort* h_bf   = (ushort*)carve((size_t)C * DMODEL * 2);
    ushort* qkv_bf = (ushort*)carve((size_t)C * D3 * 2);
    ushort* o_bf   = (ushort*)carve((size_t)C * DMODEL * 2);
    ushort* mid_bf = (ushort*)carve((size_t)C * D4 * 2);
    ushort* wt_a   = (ushort*)carve((size_t)D3 * DMODEL * 2);
    ushort* wt_p   = (ushort*)carve((size_t)DMODEL * DMODEL * 2);
    ushort* wt_f   = (ushort*)carve((size_t)D4 * DMODEL * 2);
    ushort* wt_m   = (ushort*)carve((size_t)DMODEL * D4 * 2);
    ushort* wt_out = (ushort*)carve((size_t)NVPAD * DMODEL * 2);
    ushort* Kimg   = (ushort*)carve((size_t)NHEAD * (C / KVBLK) * 4096 * 2);
    ushort* Vimg   = (ushort*)carve((size_t)NHEAD * (C / KVBLK) * 4096 * 2);

    if (ws_size >= used) {
        // ================= bf16 MFMA path =================
        transp64<<<dim3(NVPAD / 64, DMODEL / 64), blk, 0, stream>>>(
            out_w, wt_out, DMODEL, NVOCAB);

        embed_k<<<dim3(C), blk, 0, stream>>>(tokens, vocab_embed, pos_embed, x_f);

        for (int l = 0; l < LAYERS; l++) {
            transp4<<<dim3(1728), blk, 0, stream>>>(
                att_w + (size_t)l * DMODEL * D3,
                attn_proj_w + (size_t)l * DMODEL * DMODEL,
                fc_w + (size_t)l * DMODEL * D4,
                mlp_proj_w + (size_t)l * D4 * DMODEL,
                wt_a, wt_p, wt_f, wt_m);

            ln_v2<<<dim3(C / 4), blk, 0, stream>>>(
                x_f, ln1_g + l * DMODEL, ln1_b + l * DMODEL, nullptr, h_bf);

            gemm3<128, 0, false, true><<<dim3(D3 / 128, C / 128), blk, 0, stream>>>(
                h_bf, wt_a, att_b + l * D3, nullptr, qkv_bf, D3, DMODEL);

            qkv_tiles_k<<<dim3(NHEAD, C / KVBLK), blk, 0, stream>>>(qkv_bf, Kimg, Vimg);

            attn_mfma2<<<dim3(NHEAD, 16), dim3(512), 0, stream>>>(qkv_bf, Kimg, Vimg, o_bf);

            gemm3<64, 0, true, false><<<dim3(DMODEL / 128, C / 64), blk, 0, stream>>>(
                o_bf, wt_p, attn_proj_b + l * DMODEL, h_bf, x_f, DMODEL, DMODEL);

            ln_v2<<<dim3(C / 4), blk, 0, stream>>>(
                x_f, ln2_g + l * DMODEL, ln2_b + l * DMODEL, nullptr, h_bf);

            gemm3<128, 1, false, true><<<dim3(D4 / 128, C / 128), blk, 0, stream>>>(
                h_bf, wt_f, fc_b + l * D4, nullptr, mid_bf, D4, DMODEL);

            gemm3<64, 0, true, false><<<dim3(DMODEL / 128, C / 64), blk, 0, stream>>>(
                mid_bf, wt_m, mlp_proj_b + l * DMODEL, h_bf, x_f, DMODEL, D4);
        }

        ln_v2<<<dim3(C / 4), blk, 0, stream>>>(x_f, lnf_g, lnf_b, nullptr, h_bf);

        gemm_logits<<<dim3(1576), dim3(1024), 0, stream>>>(h_bf, wt_out, out_b, out);
        return;
    }

    // ================= fallback f32 path =================
    const size_t n_x   = (size_t)C * DMODEL;
    const size_t n_qkv = (size_t)C * D3;
    const size_t need_bytes = (3 * n_x + n_qkv + (size_t)C * D4) * sizeof(float);

    float *x, *h, *o, *qkv, *mid;
    float* ws = (float*)d_ws;
    if (ws_size >= need_bytes) {
        x = ws; h = x + n_x; o = h + n_x; qkv = o + n_x; mid = qkv + n_qkv;
    } else {
        x = ws; h = x + n_x; o = h + n_x;
        qkv = (float*)d_out; mid = qkv + n_qkv;
    }

    embed_k<<<dim3(C), blk, 0, stream>>>(tokens, vocab_embed, pos_embed, x);
    for (int l = 0; l < LAYERS; l++) {
        const float* lw;
        layernorm_k<<<dim3(C), blk, 0, stream>>>(x, ln1_g + l * DMODEL, ln1_b + l * DMODEL, h);
        lw = att_w + (size_t)l * DMODEL * D3;
        gemm_f32<<<dim3(D3 / BN, C / BM), blk, 0, stream>>>(
            h, lw, att_b + l * D3, nullptr, qkv, C, D3, DMODEL, 0);
        attn_k<<<dim3(C, NHEAD), blk, 0, stream>>>(qkv, o);
        lw = attn_proj_w + (size_t)l * DMODEL * DMODEL;
        gemm_f32<<<dim3(DMODEL / BN, C / BM), blk, 0, stream>>>(
            o, lw, attn_proj_b + l * DMODEL, h, x, C, DMODEL, DMODEL, 0);
        layernorm_k<<<dim3(C), blk, 0, stream>>>(x, ln2_g + l * DMODEL, ln2_b + l * DMODEL, h);
        lw = fc_w + (size_t)l * DMODEL * D4;
        gemm_f32<<<dim3(D4 / BN, C / BM), blk, 0, stream>>>(
            h, lw, fc_b + l * D4, nullptr, mid, C, D4, DMODEL, 1);
        lw = mlp_proj_w + (size_t)l * D4 * DMODEL;
        gemm_f32<<<dim3(DMODEL / BN, C / BM), blk, 0, stream>>>(
            mid, lw, mlp_proj_b + l * DMODEL, h, x, C, DMODEL, D4, 0);
    }
    layernorm_k<<<dim3(C), blk, 0, stream>>>(x, lnf_g, lnf_b, h);
    gemm_f32<<<dim3((NVOCAB + BN - 1) / BN, C / BM), blk, 0, stream>>>(
        h, out_w, out_b, nullptr, out, C, NVOCAB, DMODEL, 0);
}

// Round 24
// 844.070 us; speedup vs baseline: 1.0937x; 1.0338x over previous
//
#include <hip/hip_runtime.h>
#include <hip/hip_bf16.h>
#include <math.h>

// Problem constants
#define LAYERS 4
#define NHEAD  12
#define DMODEL 768
#define HEADD  64
#define NCTX   2048
#define NVOCAB 50257
#define NVPAD  50432            // 788*64 = 197*256
#define D3     (3*DMODEL)
#define D4     (4*DMODEL)

typedef short short8 __attribute__((ext_vector_type(8)));
typedef float f32x4  __attribute__((ext_vector_type(4)));
typedef float f32x4u __attribute__((ext_vector_type(4), aligned(4)));
typedef ushort ushx4 __attribute__((ext_vector_type(4)));

__device__ __forceinline__ float bf2f(ushort u) {
    union { uint i; float f; } c; c.i = ((uint)u) << 16; return c.f;
}
__device__ __forceinline__ ushort f2bf(float f) {
    union { float f; uint i; } c; c.f = f;
    uint i = c.i;
    uint r = (i + 0x7FFFu + ((i >> 16) & 1u)) >> 16;   // round-nearest-even
    return (ushort)r;
}

#define GLD16(gp, lp) __builtin_amdgcn_global_load_lds( \
    (__attribute__((address_space(1))) void*)(gp),      \
    (__attribute__((address_space(3))) void*)(lp), 16, 0, 0)

// vmcnt-only wait + raw barrier (no lgkmcnt drain)
#define BARS() do { asm volatile("s_waitcnt vmcnt(0)" ::: "memory"); \
                    __builtin_amdgcn_s_barrier(); } while (0)

// ---------------------------------------------------------------------------
// Embedding
// ---------------------------------------------------------------------------
__global__ void embed_k(const int* __restrict__ tok,
                        const float* __restrict__ ve,
                        const float* __restrict__ pe,
                        float* __restrict__ x) {
    int c = blockIdx.x;
    int t = tok[c];
    for (int d = threadIdx.x; d < DMODEL; d += blockDim.x)
        x[(size_t)c * DMODEL + d] = ve[(size_t)t * DMODEL + d] + pe[(size_t)c * DMODEL + d];
}

// ---------------------------------------------------------------------------
// LayerNorm: one wave per row, single pass, shuffle-only.
// ---------------------------------------------------------------------------
__global__ __launch_bounds__(256) void ln_v2(const float* __restrict__ x,
                                             const float* __restrict__ g,
                                             const float* __restrict__ b,
                                             float* __restrict__ yf,
                                             ushort* __restrict__ ybf) {
    const int w = threadIdx.x >> 6, l = threadIdx.x & 63;
    const int row = blockIdx.x * 4 + w;
    const float* xr = x + (size_t)row * DMODEL;

    f32x4 v[3];
    float s = 0.f, ss = 0.f;
    #pragma unroll
    for (int i = 0; i < 3; i++) {
        v[i] = *(const f32x4*)(xr + (l + 64 * i) * 4);
        #pragma unroll
        for (int k = 0; k < 4; k++) { s += v[i][k]; ss += v[i][k] * v[i][k]; }
    }
    #pragma unroll
    for (int off = 32; off > 0; off >>= 1) {
        s  += __shfl_xor(s, off);
        ss += __shfl_xor(ss, off);
    }
    const float mu = s * (1.f / DMODEL);
    const float var = ss * (1.f / DMODEL) - mu * mu;
    const float rstd = rsqrtf(var + 1e-5f);

    #pragma unroll
    for (int i = 0; i < 3; i++) {
        const int idx = l + 64 * i;
        f32x4 g4 = *(const f32x4*)(g + idx * 4);
        f32x4 b4 = *(const f32x4*)(b + idx * 4);
        f32x4 r;
        #pragma unroll
        for (int k = 0; k < 4; k++) r[k] = (v[i][k] - mu) * rstd * g4[k] + b4[k];
        if (yf) *(f32x4*)(yf + (size_t)row * DMODEL + idx * 4) = r;
        if (ybf) {
            ushx4 u;
            #pragma unroll
            for (int k = 0; k < 4; k++) u[k] = f2bf(r[k]);
            *(ushx4*)(ybf + (size_t)row * DMODEL + idx * 4) = u;
        }
    }
}

// ---------------------------------------------------------------------------
// Transpose + f32->bf16, 64x64 tiles, coalesced lane mapping.
// ---------------------------------------------------------------------------
__device__ __forceinline__ void transp64_body(const float* __restrict__ src,
                                              ushort* __restrict__ dst,
                                              int K, int N, int nt, int kt) {
    __shared__ float tile[64][65];
    const int t = threadIdx.x;

    {
        const int r0 = t >> 4;          // 0..15
        const int c  = (t & 15) * 4;    // 0..60
        #pragma unroll
        for (int i = 0; i < 4; i++) {
            const int r = r0 + i * 16;
            const int n = nt + c;
            const float* srow = src + (size_t)(kt + r) * N;
            f32x4 v;
            if (n + 3 < N) {
                v = *(const f32x4u*)(srow + n);
            } else {
                #pragma unroll
                for (int e = 0; e < 4; e++)
                    v[e] = (n + e < N) ? srow[n + e] : 0.f;
            }
            #pragma unroll
            for (int e = 0; e < 4; e++) tile[r][c + e] = v[e];
        }
    }
    __syncthreads();
    {
        const int nl0 = t >> 3;         // 0..31
        const int kb  = (t & 7) * 8;    // 0..56
        #pragma unroll
        for (int h = 0; h < 2; h++) {
            const int nl = nl0 + h * 32;
            short8 o;
            #pragma unroll
            for (int j = 0; j < 8; j++)
                o[j] = (short)f2bf(tile[kb + j][nl]);
            *(short8*)(dst + (size_t)(nt + nl) * K + kt + kb) = o;
        }
    }
}

__global__ __launch_bounds__(256) void transp64(const float* __restrict__ src,
                                                ushort* __restrict__ dst,
                                                int K, int N) {
    transp64_body(src, dst, K, N, blockIdx.x * 64, blockIdx.y * 64);
}

// ---------------------------------------------------------------------------
// Fused per-layer weight transposes. Grid 1728 = 432 + 144 + 576 + 576.
// ---------------------------------------------------------------------------
__global__ __launch_bounds__(256) void transp4(
    const float* __restrict__ s0, const float* __restrict__ s1,
    const float* __restrict__ s2, const float* __restrict__ s3,
    ushort* __restrict__ d0, ushort* __restrict__ d1,
    ushort* __restrict__ d2, ushort* __restrict__ d3)
{
    const int bid = blockIdx.x;
    const float* src; ushort* dst; int K, N, nx, tb;
    if (bid < 432)       { src = s0; dst = d0; K = 768;  N = 2304; nx = 36; tb = bid; }
    else if (bid < 576)  { src = s1; dst = d1; K = 768;  N = 768;  nx = 12; tb = bid - 432; }
    else if (bid < 1152) { src = s2; dst = d2; K = 768;  N = 3072; nx = 48; tb = bid - 576; }
    else                 { src = s3; dst = d3; K = 3072; N = 768;  nx = 12; tb = bid - 1152; }
    transp64_body(src, dst, K, N, (tb % nx) * 64, (tb / nx) * 64);
}

// ===========================================================================
// Layer GEMM v3: counted-vmcnt 3-buffer pipeline. 256 thr, MTx128, BK=32.
// HASADD residual source is bf16.
// ===========================================================================
template<int MT, int ACT, bool HASADD, bool OUTBF>
__global__ __launch_bounds__(256) void gemm3(
    const ushort* __restrict__ A, const ushort* __restrict__ Bt,
    const float* __restrict__ bias, const ushort* __restrict__ addsrc,
    void* __restrict__ Cout, int N, int K)
{
    constexpr int AFR  = MT / 32;
    constexpr int ABYT = MT * 64;
    constexpr int BUF  = ABYT + 8192;
    constexpr int LPS  = MT / 64 + 2;
    __shared__ __align__(16) char smem[3 * BUF];
    const int bm = blockIdx.y * MT, bn = blockIdx.x * 128;
    const int t = threadIdx.x, l = t & 63, w = t >> 6;
    const int wrb = (w >> 1) * (MT / 2), wcb = (w & 1) * 64;
    const int l15 = l & 15, lg = l >> 4;
    const int swr = ((l15 >> 1) & 3) << 4;

    const int srow = t >> 2;
    const int ssc  = ((t & 3) ^ ((srow >> 1) & 3)) * 8;
    const ushort* Abase = A  + (size_t)(bm + srow) * K + ssc;
    const ushort* Bbase = Bt + (size_t)(bn + srow) * K + ssc;

    f32x4 acc[AFR][4];
    #pragma unroll
    for (int i = 0; i < AFR; i++)
        #pragma unroll
        for (int j = 0; j < 4; j++) acc[i][j] = (f32x4)0.f;

    auto STAGE = [&](int buf, int ke) {
        ushort* as = (ushort*)(smem + buf * BUF);
        ushort* bs = (ushort*)(smem + buf * BUF + ABYT);
        #pragma unroll
        for (int i = 0; i < MT / 64; i++)
            GLD16(Abase + (size_t)i * 64 * K + ke, as + (t + i * 256) * 8);
        #pragma unroll
        for (int i = 0; i < 2; i++)
            GLD16(Bbase + (size_t)i * 64 * K + ke, bs + (t + i * 256) * 8);
    };
    auto COMPUTE = [&](int buf) {
        const char* as = smem + buf * BUF;
        const char* bs = smem + buf * BUF + ABYT;
        short8 af[AFR], bfr[4];
        #pragma unroll
        for (int f = 0; f < AFR; f++)
            af[f] = *(const short8*)(as + (((wrb + f * 16 + l15) * 64 + lg * 16) ^ swr));
        #pragma unroll
        for (int f = 0; f < 4; f++)
            bfr[f] = *(const short8*)(bs + (((wcb + f * 16 + l15) * 64 + lg * 16) ^ swr));
        __builtin_amdgcn_s_setprio(1);
        #pragma unroll
        for (int fm = 0; fm < AFR; fm++)
            #pragma unroll
            for (int fn = 0; fn < 4; fn++)
                acc[fm][fn] = __builtin_amdgcn_mfma_f32_16x16x32_bf16(
                    af[fm], bfr[fn], acc[fm][fn], 0, 0, 0);
        __builtin_amdgcn_s_setprio(0);
    };

    const int nk = K >> 5;
    STAGE(0, 0);
    STAGE(1, 32);
    int bc = 0, bs2 = 2;                      // compute buf, stage buf
    for (int kt = 0; kt < nk; kt++) {
        if (kt < nk - 1)
            asm volatile("s_waitcnt vmcnt(%0)" :: "i"(LPS) : "memory");
        else
            asm volatile("s_waitcnt vmcnt(0)" ::: "memory");
        __builtin_amdgcn_s_barrier();
        asm volatile("" ::: "memory");
        if (kt + 2 < nk) STAGE(bs2, (kt + 2) << 5);
        COMPUTE(bc);
        bc  = (bc  == 2) ? 0 : bc  + 1;
        bs2 = (bs2 == 2) ? 0 : bs2 + 1;
    }

    #pragma unroll
    for (int fn = 0; fn < 4; fn++) {
        const int col = bn + wcb + fn * 16 + l15;
        const float bi = bias[col];
        #pragma unroll
        for (int fm = 0; fm < AFR; fm++) {
            #pragma unroll
            for (int j = 0; j < 4; j++) {
                const int row = bm + wrb + fm * 16 + lg * 4 + j;
                float v = acc[fm][fn][j] + bi;
                if (ACT == 1) {
                    float u = 0.7978845608028654f * (v + 0.044715f * v * v * v);
                    v = 0.5f * v * (1.f + tanhf(u));
                }
                if (HASADD) v += bf2f(addsrc[(size_t)row * N + col]);
                if (OUTBF) ((ushort*)Cout)[(size_t)row * N + col] = f2bf(v);
                else       ((float*) Cout)[(size_t)row * N + col] = v;
            }
        }
    }
}

// ---------------------------------------------------------------------------
// Logits GEMM: 256x256 tile, 1024 threads (16 waves, 4M x 4N), BK=32.
// 3-buffer counted-vmcnt pipeline (96 KB LDS, 4 waves/SIMD).
// XCD-chunked bijective mapping over 1576 = 8*197 blocks.
// 4-pass LDS-staged f32 epilogue (contiguous coalesced rows).
// ---------------------------------------------------------------------------
__global__ __launch_bounds__(1024) void gemm_logits(
    const ushort* __restrict__ A, const ushort* __restrict__ Bt,
    const float* __restrict__ bias, float* __restrict__ Cout)
{
    __shared__ __align__(16) char smem[98304];   // 3 x (16 KB A + 16 KB B)
    float* Cs = (float*)smem;                     // epilogue: 64 x 256 f32

    const int pid = (blockIdx.x & 7) * 197 + (blockIdx.x >> 3);
    const int np = pid >> 3, mt = pid & 7;
    const int bm = mt * 256, bn = np * 256;
    const int t = threadIdx.x, l = t & 63, w = t >> 6;   // w 0..15
    const int wm = w >> 2, wn = w & 3;          // 4 x 4 wave grid
    const int l15 = l & 15, lg = l >> 4;
    const int swr = ((l15 >> 1) & 3) << 4;

    const int sr  = t >> 2;                     // 0..255
    const int ssc = ((t & 3) ^ ((sr >> 1) & 3)) * 8;
    const ushort* Ab = A  + (size_t)(bm + sr) * DMODEL + ssc;
    const ushort* Bb = Bt + (size_t)(bn + sr) * DMODEL + ssc;

    f32x4 acc[4][4];
    #pragma unroll
    for (int i = 0; i < 4; i++)
        #pragma unroll
        for (int j = 0; j < 4; j++) acc[i][j] = (f32x4)0.f;

    auto STAGE = [&](int buf, int ke) {
        ushort* as = (ushort*)(smem + buf * 32768);
        ushort* bs = (ushort*)(smem + buf * 32768 + 16384);
        GLD16(Ab + ke, as + t * 8);
        GLD16(Bb + ke, bs + t * 8);
    };
    auto COMPUTE = [&](int buf) {
        const char* as = smem + buf * 32768;
        const char* bs = smem + buf * 32768 + 16384;
        short8 bfr[4];
        #pragma unroll
        for (int f = 0; f < 4; f++) {
            const int r = wn * 64 + f * 16 + l15;
            bfr[f] = *(const short8*)(bs + ((r * 64 + lg * 16) ^ swr));
        }
        __builtin_amdgcn_s_setprio(1);
        #pragma unroll
        for (int fm = 0; fm < 4; fm++) {
            const int r = wm * 64 + fm * 16 + l15;
            short8 af = *(const short8*)(as + ((r * 64 + lg * 16) ^ swr));
            #pragma unroll
            for (int fn = 0; fn < 4; fn++)
                acc[fm][fn] = __builtin_amdgcn_mfma_f32_16x16x32_bf16(
                    af, bfr[fn], acc[fm][fn], 0, 0, 0);
        }
        __builtin_amdgcn_s_setprio(0);
    };

    STAGE(0, 0);
    STAGE(1, 32);
    #pragma unroll
    for (int kt = 0; kt < 24; kt++) {
        if (kt <= 22) asm volatile("s_waitcnt vmcnt(2)" ::: "memory");
        else          asm volatile("s_waitcnt vmcnt(0)" ::: "memory");
        __builtin_amdgcn_s_barrier();
        asm volatile("" ::: "memory");
        if (kt + 2 < 24) STAGE((kt + 2) % 3, (kt + 2) * 32);
        COMPUTE(kt % 3);
    }

    // Epilogue: 4 passes of 64 rows via LDS (first 64 KB of smem).
    #pragma unroll
    for (int p = 0; p < 4; p++) {
        __syncthreads();
        if (wm == p) {
            #pragma unroll
            for (int fm = 0; fm < 4; fm++) {
                #pragma unroll
                for (int fn = 0; fn < 4; fn++) {
                    const int ccol = wn * 64 + fn * 16 + l15;
                    const int gcol = bn + ccol;
                    const float bi = (gcol < NVOCAB) ? bias[gcol] : 0.f;
                    #pragma unroll
                    for (int j = 0; j < 4; j++)
                        Cs[(fm * 16 + lg * 4 + j) * 256 + ccol] = acc[fm][fn][j] + bi;
                }
            }
        }
        __syncthreads();
        const int grow0 = bm + p * 64;
        #pragma unroll
        for (int i = 0; i < 4; i++) {
            const int idx = t + i * 1024;
            const int rr = idx >> 6, ch = idx & 63;
            f32x4 v = *(const f32x4*)(Cs + rr * 256 + ch * 4);
            float* dst = Cout + (size_t)(grow0 + rr) * NVOCAB + bn + ch * 4;
            if (bn + 256 <= NVOCAB) {
                *(f32x4u*)dst = v;
            } else {
                #pragma unroll
                for (int e = 0; e < 4; e++)
                    if (bn + ch * 4 + e < NVOCAB) dst[e] = v[e];
            }
        }
    }
}

// ---------------------------------------------------------------------------
// Build per-(head, kv-tile) swizzled K and V^T tile images (8 KB each).
// ---------------------------------------------------------------------------
#define QBLK  64
#define KVBLK 64
__global__ __launch_bounds__(256) void qkv_tiles_k(const ushort* __restrict__ qkv,
                                                   ushort* __restrict__ Kimg,
                                                   ushort* __restrict__ Vimg) {
    __shared__ __align__(16) ushort Vt_l[4096];
    const int h = blockIdx.x;
    const int kt = blockIdx.y;
    const int k0 = kt * KVBLK;
    const int t = threadIdx.x;
    ushort* kd = Kimg + ((size_t)h * (NCTX / KVBLK) + kt) * 4096;
    ushort* vd = Vimg + ((size_t)h * (NCTX / KVBLK) + kt) * 4096;

    #pragma unroll
    for (int i = 0; i < 2; i++) {
        const int c = t + i * 256;
        const int r = c >> 3, cc = c & 7;
        short8 kv8 = *(const short8*)(qkv + (size_t)(k0 + r) * D3 + DMODEL + h * HEADD + cc * 8);
        *(short8*)(kd + (((r * 8 + cc) ^ (r & 7)) * 8)) = kv8;
        short8 vv = *(const short8*)(qkv + (size_t)(k0 + r) * D3 + 2 * DMODEL + h * HEADD + cc * 8);
        #pragma unroll
        for (int j = 0; j < 8; j++) {
            const int d = cc * 8 + j;
            const int addr = (d * 128 + r * 2) ^ ((d & 7) << 4);
            *(ushort*)((char*)Vt_l + addr) = (ushort)vv[j];
        }
    }
    __syncthreads();
    #pragma unroll
    for (int i = 0; i < 2; i++) {
        const int c = t + i * 256;
        *(short8*)(vd + c * 8) = *(const short8*)(Vt_l + c * 8);
    }
}

// ---------------------------------------------------------------------------
// One attention stream step, NO-MAX softmax variant.
// ---------------------------------------------------------------------------
__device__ __forceinline__ void attn_step(
    const short8 qf[2], f32x4 Of[4], float lpart[4],
    const ushort* Kt, const ushort* Vt, char* pw,
    int k0, int q0, int maskTile, int w, int l15, int lg)
{
    const float scale = 0.125f;
    f32x4 S[4];
    __builtin_amdgcn_s_setprio(1);
    #pragma unroll
    for (int nf = 0; nf < 4; nf++) {
        f32x4 a = (f32x4)0.f;
        #pragma unroll
        for (int s = 0; s < 2; s++) {
            const int r = nf * 16 + l15;
            const int addr = (r * 128 + s * 64 + lg * 16) ^ ((r & 7) << 4);
            short8 kf = *(const short8*)((const char*)Kt + addr);
            a = __builtin_amdgcn_mfma_f32_16x16x32_bf16(qf[s], kf, a, 0, 0, 0);
        }
        S[nf] = a;
    }
    __builtin_amdgcn_s_setprio(0);

    float p[4][4];
    if (maskTile) {
        #pragma unroll
        for (int nf = 0; nf < 4; nf++) {
            const int kvg = k0 + nf * 16 + l15;
            #pragma unroll
            for (int j = 0; j < 4; j++) {
                const int qg = q0 + w * 16 + lg * 4 + j;
                p[nf][j] = (kvg <= qg) ? __expf(S[nf][j] * scale) : 0.f;
            }
        }
    } else {
        #pragma unroll
        for (int nf = 0; nf < 4; nf++)
            #pragma unroll
            for (int j = 0; j < 4; j++)
                p[nf][j] = __expf(S[nf][j] * scale);
    }

    #pragma unroll
    for (int j = 0; j < 4; j++)
        lpart[j] += (p[0][j] + p[1][j]) + (p[2][j] + p[3][j]);

    #pragma unroll
    for (int nf = 0; nf < 4; nf++)
        #pragma unroll
        for (int j = 0; j < 4; j++) {
            const int ql = lg * 4 + j;
            const int addr = (ql * 128 + (nf * 16 + l15) * 2) ^ ((ql & 7) << 4);
            *(ushort*)(pw + addr) = f2bf(p[nf][j]);
        }

    __builtin_amdgcn_s_setprio(1);
    #pragma unroll
    for (int s = 0; s < 2; s++) {
        const int paddr = (l15 * 128 + s * 64 + lg * 16) ^ ((l15 & 7) << 4);
        short8 pf = *(const short8*)(pw + paddr);
        #pragma unroll
        for (int df = 0; df < 4; df++) {
            const int r = df * 16 + l15;
            const int vaddr = (r * 128 + s * 64 + lg * 16) ^ ((r & 7) << 4);
            short8 vf = *(const short8*)((const char*)Vt + vaddr);
            Of[df] = __builtin_amdgcn_mfma_f32_16x16x32_bf16(pf, vf, Of[df], 0, 0, 0);
        }
    }
    __builtin_amdgcn_s_setprio(0);
}

// ---------------------------------------------------------------------------
// MFMA flash attention, 8 waves, KV-SPLIT: one q-tile per block (grid 12x32,
// longest-first for LPT). Waves 0-3 process EVEN kv tiles, waves 4-7 ODD
// tiles, each with private Of/lpart; one LDS exchange (reusing dead Ks
// buffer) merges the halves. Quad staging per barrier period as before.
// Critical path per block: ceil((qT+1)/2) steps vs max(qT+1, 32-qT) before.
// ---------------------------------------------------------------------------
__global__ __launch_bounds__(512) void attn_mfma2(const ushort* __restrict__ qkv,
                                                  const ushort* __restrict__ Kimg,
                                                  const ushort* __restrict__ Vimg,
                                                  ushort* __restrict__ o) {
    const int h   = blockIdx.x;
    const int myqT = 31 - blockIdx.y;    // longest blocks dispatched first
    const int t = threadIdx.x;
    const int w = t >> 6;                // 0..7
    const int strm = w >> 2;             // kv parity: 0 = even tiles, 1 = odd
    const int ws = w & 3;                // row-group within q-tile
    const int l = t & 63;
    const int l15 = l & 15, lg = l >> 4;

    __shared__ __align__(16) ushort Ks[2][16384];  // 2 x quad of 64-tiles
    __shared__ __align__(16) ushort Vs[2][16384];
    __shared__ __align__(16) ushort Ps[8][1024];

    const int q0 = myqT * QBLK;
    const ushort* kbase = Kimg + (size_t)h * (NCTX / KVBLK) * 4096;
    const ushort* vbase = Vimg + (size_t)h * (NCTX / KVBLK) * 4096;
    char* pw = (char*)&Ps[w][0];

    short8 qf[2];
    {
        const int qr = q0 + ws * 16 + l15;
        #pragma unroll
        for (int s = 0; s < 2; s++)
            qf[s] = *(const short8*)(qkv + (size_t)qr * D3 + h * HEADD + s * 32 + lg * 8);
    }

    f32x4 Of[4];
    float lpart[4];
    #pragma unroll
    for (int i = 0; i < 4; i++) {
        Of[i] = (f32x4)0.f;
        lpart[i] = 0.f;
    }

    const int ntiles = myqT + 1;             // 1..32 (64-col tiles)
    const int nsteps = (ntiles + 3) >> 2;    // quads (<= 8)

    // prologue: stage quad 0 (tiles 0-3 = 16384 contiguous ushorts per array)
    #pragma unroll
    for (int i = 0; i < 4; i++) {
        GLD16(kbase + (size_t)(t + i * 512) * 8, &Ks[0][(t + i * 512) * 8]);
        GLD16(vbase + (size_t)(t + i * 512) * 8, &Vs[0][(t + i * 512) * 8]);
    }

    for (int st = 0; st < nsteps; st++) {
        const int cur = st & 1;
        __syncthreads();                      // quad(st) staged; other buf free
        if (st + 1 < nsteps) {                // prefetch next quad
            const ushort* kim = kbase + (size_t)(st + 1) * 16384;
            const ushort* vim = vbase + (size_t)(st + 1) * 16384;
            #pragma unroll
            for (int i = 0; i < 4; i++) {
                GLD16(kim + (size_t)(t + i * 512) * 8, &Ks[cur ^ 1][(t + i * 512) * 8]);
                GLD16(vim + (size_t)(t + i * 512) * 8, &Vs[cur ^ 1][(t + i * 512) * 8]);
            }
        }
        // wave-group strm handles sub-tiles of matching parity (kt & 1 == strm)
        #pragma unroll
        for (int sub2 = 0; sub2 < 2; sub2++) {
            const int sub = sub2 * 2 + strm;
            const int kt = st * 4 + sub;
            if (kt < ntiles)
                attn_step(qf, Of, lpart,
                          &Ks[cur][sub * 4096], &Vs[cur][sub * 4096], pw,
                          kt * KVBLK, q0, (kt == myqT) ? 1 : 0, ws, l15, lg);
        }
    }

    // Merge the two kv-parity halves. Ks is dead now; reuse as f32 scratch.
    // Stride 21 floats (84 B) -> conflict-light.
    __syncthreads();                           // all waves done with Ks/Vs
    float* scr = (float*)&Ks[0][0];            // 256 lanes x 21 f32 = 21.5 KB
    const int sidx = (ws * 64 + l) * 21;
    if (strm == 1) {
        #pragma unroll
        for (int df = 0; df < 4; df++)
            #pragma unroll
            for (int j = 0; j < 4; j++)
                scr[sidx + df * 4 + j] = Of[df][j];
        #pragma unroll
        for (int j = 0; j < 4; j++)
            scr[sidx + 16 + j] = lpart[j];
    }
    __syncthreads();
    if (strm == 0) {
        #pragma unroll
        for (int df = 0; df < 4; df++)
            #pragma unroll
            for (int j = 0; j < 4; j++)
                Of[df][j] += scr[sidx + df * 4 + j];
        #pragma unroll
        for (int j = 0; j < 4; j++)
            lpart[j] += scr[sidx + 16 + j];

        #pragma unroll
        for (int j = 0; j < 4; j++) {
            float lsum = lpart[j];
            lsum += __shfl_xor(lsum, 1);
            lsum += __shfl_xor(lsum, 2);
            lsum += __shfl_xor(lsum, 4);
            lsum += __shfl_xor(lsum, 8);
            const float inv = 1.f / lsum;
            const int qg = q0 + ws * 16 + lg * 4 + j;
            #pragma unroll
            for (int df = 0; df < 4; df++)
                o[(size_t)qg * DMODEL + h * HEADD + df * 16 + l15] = f2bf(Of[df][j] * inv);
        }
    }
}

// ===========================================================================
// Fallback f32 path (only if ws too small)
// ===========================================================================
__global__ void layernorm_k(const float* __restrict__ x,
                            const float* __restrict__ g,
                            const float* __restrict__ b,
                            float* __restrict__ y) {
    const int row = blockIdx.x;
    const float* xr = x + (size_t)row * DMODEL;
    __shared__ float red[256];
    const int tid = threadIdx.x;
    float s = 0.f;
    for (int d = tid; d < DMODEL; d += 256) s += xr[d];
    red[tid] = s; __syncthreads();
    for (int off = 128; off > 0; off >>= 1) {
        if (tid < off) red[tid] += red[tid + off];
        __syncthreads();
    }
    const float mu = red[0] / DMODEL;
    __syncthreads();
    float v = 0.f;
    for (int d = tid; d < DMODEL; d += 256) { float tv = xr[d] - mu; v += tv * tv; }
    red[tid] = v; __syncthreads();
    for (int off = 128; off > 0; off >>= 1) {
        if (tid < off) red[tid] += red[tid + off];
        __syncthreads();
    }
    const float rstd = rsqrtf(red[0] / DMODEL + 1e-5f);
    for (int d = tid; d < DMODEL; d += 256)
        y[(size_t)row * DMODEL + d] = (xr[d] - mu) * rstd * g[d] + b[d];
}

#define BM 64
#define BN 64
#define BK 16
__global__ __launch_bounds__(256)
void gemm_f32(const float* __restrict__ A, const float* __restrict__ B,
              const float* __restrict__ bias, const float* __restrict__ addsrc,
              float* __restrict__ C, int M, int N, int K, int act) {
    __shared__ float As[BK][BM];
    __shared__ float Bs[BK][BN];
    const int bm = blockIdx.y * BM;
    const int bn = blockIdx.x * BN;
    const int tid = threadIdx.x;
    const int tr = tid >> 4;
    const int tc = tid & 15;
    float acc[4][4] = {};
    for (int k0 = 0; k0 < K; k0 += BK) {
        #pragma unroll
        for (int i = 0; i < 4; i++) {
            int idx = tid + i * 256;
            int row = idx >> 4, col = idx & 15;
            int gm = bm + row;
            float v = 0.f;
            if (gm < M) v = A[(size_t)gm * K + (k0 + col)];
            As[col][row] = v;
        }
        #pragma unroll
        for (int i = 0; i < 4; i++) {
            int idx = tid + i * 256;
            int row = idx >> 6, col = idx & 63;
            int gn = bn + col;
            float v = 0.f;
            if (gn < N) v = B[(size_t)(k0 + row) * N + gn];
            Bs[row][col] = v;
        }
        __syncthreads();
        #pragma unroll
        for (int kk = 0; kk < BK; kk++) {
            float a[4], bb[4];
            #pragma unroll
            for (int i = 0; i < 4; i++) a[i] = As[kk][tr * 4 + i];
            #pragma unroll
            for (int j = 0; j < 4; j++) bb[j] = Bs[kk][tc * 4 + j];
            #pragma unroll
            for (int i = 0; i < 4; i++)
                #pragma unroll
                for (int j = 0; j < 4; j++)
                    acc[i][j] += a[i] * bb[j];
        }
        __syncthreads();
    }
    #pragma unroll
    for (int i = 0; i < 4; i++) {
        int gm = bm + tr * 4 + i;
        if (gm >= M) continue;
        #pragma unroll
        for (int j = 0; j < 4; j++) {
            int gn = bn + tc * 4 + j;
            if (gn >= N) continue;
            float v = acc[i][j] + (bias ? bias[gn] : 0.f);
            if (act == 1) {
                const float cst = 0.7978845608028654f;
                float tt = tanhf(cst * (v + 0.044715f * v * v * v));
                v = 0.5f * v * (1.f + tt);
            }
            if (addsrc) v += addsrc[(size_t)gm * N + gn];
            C[(size_t)gm * N + gn] = v;
        }
    }
}

__global__ __launch_bounds__(256)
void attn_k(const float* __restrict__ qkv, float* __restrict__ o) {
    const int q = blockIdx.x;
    const int h = blockIdx.y;
    const int tid = threadIdx.x;
    __shared__ float qrow[HEADD];
    __shared__ float sc[NCTX];
    __shared__ float red[256];
    __shared__ float part[4][HEADD];
    if (tid < HEADD) qrow[tid] = qkv[(size_t)q * D3 + h * HEADD + tid];
    __syncthreads();
    const float scale = 0.125f;
    float lmax = -1e30f;
    for (int k = tid; k <= q; k += 256) {
        const float* kr = qkv + (size_t)k * D3 + DMODEL + h * HEADD;
        float s = 0.f;
        #pragma unroll
        for (int d = 0; d < HEADD; d++) s += qrow[d] * kr[d];
        s *= scale;
        sc[k] = s;
        lmax = fmaxf(lmax, s);
    }
    red[tid] = lmax; __syncthreads();
    for (int off = 128; off > 0; off >>= 1) {
        if (tid < off) red[tid] = fmaxf(red[tid], red[tid + off]);
        __syncthreads();
    }
    const float m = red[0];
    __syncthreads();
    float lsum = 0.f;
    for (int k = tid; k <= q; k += 256) {
        float p = expf(sc[k] - m);
        sc[k] = p;
        lsum += p;
    }
    red[tid] = lsum; __syncthreads();
    for (int off = 128; off > 0; off >>= 1) {
        if (tid < off) red[tid] += red[tid + off];
        __syncthreads();
    }
    const float inv = 1.f / red[0];
    const int grp = tid >> 6;
    const int d = tid & 63;
    float acc = 0.f;
    for (int k = grp; k <= q; k += 4)
        acc += sc[k] * qkv[(size_t)k * D3 + 2 * DMODEL + h * HEADD + d];
    part[grp][d] = acc;
    __syncthreads();
    if (tid < HEADD) {
        float v = (part[0][tid] + part[1][tid] + part[2][tid] + part[3][tid]) * inv;
        o[(size_t)q * DMODEL + h * HEADD + tid] = v;
    }
}

// ---------------------------------------------------------------------------
// Launch
// ---------------------------------------------------------------------------
extern "C" void kernel_launch(void* const* d_in, const int* in_sizes, int n_in,
                              void* d_out, int out_size, void* d_ws, size_t ws_size,
                              hipStream_t stream) {
    const int*   tokens      = (const int*)  d_in[0];
    const float* vocab_embed = (const float*)d_in[1];
    const float* pos_embed   = (const float*)d_in[2];
    const float* ln1_g       = (const float*)d_in[3];
    const float* ln1_b       = (const float*)d_in[4];
    const float* att_w       = (const float*)d_in[5];
    const float* att_b       = (const float*)d_in[6];
    const float* attn_proj_w = (const float*)d_in[7];
    const float* attn_proj_b = (const float*)d_in[8];
    const float* ln2_g       = (const float*)d_in[9];
    const float* ln2_b       = (const float*)d_in[10];
    const float* fc_w        = (const float*)d_in[11];
    const float* fc_b        = (const float*)d_in[12];
    const float* mlp_proj_w  = (const float*)d_in[13];
    const float* mlp_proj_b  = (const float*)d_in[14];
    const float* lnf_g       = (const float*)d_in[15];
    const float* lnf_b       = (const float*)d_in[16];
    const float* out_w       = (const float*)d_in[17];
    const float* out_b       = (const float*)d_in[18];
    float* out = (float*)d_out;

    const int C = NCTX;
    dim3 blk(256);

    // ---- workspace carve for bf16 path ----
    char* wp = (char*)d_ws;
    size_t used = 0;
    auto carve = [&](size_t bytes) -> void* {
        bytes = (bytes + 255) & ~(size_t)255;
        void* p = wp + used;
        used += bytes;
        return p;
    };
    float*  x_f    = (float*) carve((size_t)C * DMODEL * 4);
    ushort* h_bf   = (ushort*)carve((size_t)C * DMODEL * 2);
    ushort* qkv_bf = (ushort*)carve((size_t)C * D3 * 2);
    ushort* o_bf   = (ushort*)carve((size_t)C * DMODEL * 2);
    ushort* mid_bf = (ushort*)carve((size_t)C * D4 * 2);
    ushort* wt_a   = (ushort*)carve((size_t)D3 * DMODEL * 2);
    ushort* wt_p   = (ushort*)carve((size_t)DMODEL * DMODEL * 2);
    ushort* wt_f   = (ushort*)carve((size_t)D4 * DMODEL * 2);
    ushort* wt_m   = (ushort*)carve((size_t)DMODEL * D4 * 2);
    ushort* wt_out = (ushort*)carve((size_t)NVPAD * DMODEL * 2);
    ushort* Kimg   = (ushort*)carve((size_t)NHEAD * (C / KVBLK) * 4096 * 2);
    ushort* Vimg   = (ushort*)carve((size_t)NHEAD * (C / KVBLK) * 4096 * 2);

    if (ws_size >= used) {
        // ================= bf16 MFMA path =================
        transp64<<<dim3(NVPAD / 64, DMODEL / 64), blk, 0, stream>>>(
            out_w, wt_out, DMODEL, NVOCAB);

        embed_k<<<dim3(C), blk, 0, stream>>>(tokens, vocab_embed, pos_embed, x_f);

        for (int l = 0; l < LAYERS; l++) {
            transp4<<<dim3(1728), blk, 0, stream>>>(
                att_w + (size_t)l * DMODEL * D3,
                attn_proj_w + (size_t)l * DMODEL * DMODEL,
                fc_w + (size_t)l * DMODEL * D4,
                mlp_proj_w + (size_t)l * D4 * DMODEL,
                wt_a, wt_p, wt_f, wt_m);

            ln_v2<<<dim3(C / 4), blk, 0, stream>>>(
                x_f, ln1_g + l * DMODEL, ln1_b + l * DMODEL, nullptr, h_bf);

            gemm3<128, 0, false, true><<<dim3(D3 / 128, C / 128), blk, 0, stream>>>(
                h_bf, wt_a, att_b + l * D3, nullptr, qkv_bf, D3, DMODEL);

            qkv_tiles_k<<<dim3(NHEAD, C / KVBLK), blk, 0, stream>>>(qkv_bf, Kimg, Vimg);

            attn_mfma2<<<dim3(NHEAD, 32), dim3(512), 0, stream>>>(qkv_bf, Kimg, Vimg, o_bf);

            gemm3<64, 0, true, false><<<dim3(DMODEL / 128, C / 64), blk, 0, stream>>>(
                o_bf, wt_p, attn_proj_b + l * DMODEL, h_bf, x_f, DMODEL, DMODEL);

            ln_v2<<<dim3(C / 4), blk, 0, stream>>>(
                x_f, ln2_g + l * DMODEL, ln2_b + l * DMODEL, nullptr, h_bf);

            gemm3<128, 1, false, true><<<dim3(D4 / 128, C / 128), blk, 0, stream>>>(
                h_bf, wt_f, fc_b + l * D4, nullptr, mid_bf, D4, DMODEL);

            gemm3<64, 0, true, false><<<dim3(DMODEL / 128, C / 64), blk, 0, stream>>>(
                mid_bf, wt_m, mlp_proj_b + l * DMODEL, h_bf, x_f, DMODEL, D4);
        }

        ln_v2<<<dim3(C / 4), blk, 0, stream>>>(x_f, lnf_g, lnf_b, nullptr, h_bf);

        gemm_logits<<<dim3(1576), dim3(1024), 0, stream>>>(h_bf, wt_out, out_b, out);
        return;
    }

    // ================= fallback f32 path =================
    const size_t n_x   = (size_t)C * DMODEL;
    const size_t n_qkv = (size_t)C * D3;
    const size_t need_bytes = (3 * n_x + n_qkv + (size_t)C * D4) * sizeof(float);

    float *x, *h, *o, *qkv, *mid;
    float* ws = (float*)d_ws;
    if (ws_size >= need_bytes) {
        x = ws; h = x + n_x; o = h + n_x; qkv = o + n_x; mid = qkv + n_qkv;
    } else {
        x = ws; h = x + n_x; o = h + n_x;
        qkv = (float*)d_out; mid = qkv + n_qkv;
    }

    embed_k<<<dim3(C), blk, 0, stream>>>(tokens, vocab_embed, pos_embed, x);
    for (int l = 0; l < LAYERS; l++) {
        const float* lw;
        layernorm_k<<<dim3(C), blk, 0, stream>>>(x, ln1_g + l * DMODEL, ln1_b + l * DMODEL, h);
        lw = att_w + (size_t)l * DMODEL * D3;
        gemm_f32<<<dim3(D3 / BN, C / BM), blk, 0, stream>>>(
            h, lw, att_b + l * D3, nullptr, qkv, C, D3, DMODEL, 0);
        attn_k<<<dim3(C, NHEAD), blk, 0, stream>>>(qkv, o);
        lw = attn_proj_w + (size_t)l * DMODEL * DMODEL;
        gemm_f32<<<dim3(DMODEL / BN, C / BM), blk, 0, stream>>>(
            o, lw, attn_proj_b + l * DMODEL, h, x, C, DMODEL, DMODEL, 0);
        layernorm_k<<<dim3(C), blk, 0, stream>>>(x, ln2_g + l * DMODEL, ln2_b + l * DMODEL, h);
        lw = fc_w + (size_t)l * DMODEL * D4;
        gemm_f32<<<dim3(D4 / BN, C / BM), blk, 0, stream>>>(
            h, lw, fc_b + l * D4, nullptr, mid, C, D4, DMODEL, 1);
        lw = mlp_proj_w + (size_t)l * D4 * DMODEL;
        gemm_f32<<<dim3(DMODEL / BN, C / BM), blk, 0, stream>>>(
            mid, lw, mlp_proj_b + l * DMODEL, h, x, C, DMODEL, D4, 0);
    }
    layernorm_k<<<dim3(C), blk, 0, stream>>>(x, lnf_g, lnf_b, h);
    gemm_f32<<<dim3((NVOCAB + BN - 1) / BN, C / BM), blk, 0, stream>>>(
        h, out_w, out_b, nullptr, out, C, NVOCAB, DMODEL, 0);
}